// Round 3
// baseline (5031.961 us; speedup 1.0000x reference)
//
#include <hip/hip_runtime.h>
#include <cstdint>
#include <cstddef>

typedef _Float16 half_t;
typedef half_t half2_t __attribute__((ext_vector_type(2)));

static constexpr int TTs = 2048;   // timesteps
static constexpr int BBn = 64;     // batch
static constexpr int DINn = 64;    // input dim
static constexpr int HPn  = 256;   // proj dim
static constexpr int U0c = 135, C0c = 391, R0c = 405;   // layer0
static constexpr int U1c = 89,  C1c = 224, R1c = 267;   // layer1
static constexpr int U2c = 32,  C2c = 121, R2c = 96;    // layer2
static constexpr size_t BTn = (size_t)BBn * TTs;        // 131072

// ---------------- math helpers ----------------
__device__ __forceinline__ float tanh_f(float x) {
    return 1.f - __fdividef(2.f, __expf(2.f * x) + 1.f);
}
__device__ __forceinline__ float sigm_f(float x) {
    return __fdividef(1.f, 1.f + __expf(-x));
}
// quad butterfly sum via DPP (VALU pipe, no LDS): after this all 4 lanes of a
// quad hold the sum of their 4 values.
__device__ __forceinline__ float qsum(float v) {
    v += __builtin_bit_cast(float, __builtin_amdgcn_update_dpp(
             0, __builtin_bit_cast(int, v), 0xB1, 0xF, 0xF, true));  // quad_perm [1,0,3,2]
    v += __builtin_bit_cast(float, __builtin_amdgcn_update_dpp(
             0, __builtin_bit_cast(int, v), 0x4E, 0xF, 0xF, true));  // quad_perm [2,3,0,1]
    return v;
}

// ---------------- mask dtype probe ----------------
__device__ __forceinline__ int mask_mode(const unsigned char* mp) {
    const unsigned* wp = (const unsigned*)mp;
    bool all01 = true, allf = true;
    for (int k = 0; k < 64; ++k) {
        unsigned w = wp[k];
        all01 = all01 && (w == 0u || w == 1u);
        allf  = allf  && (w == 0u || w == 0x3F800000u);
    }
    if (all01) return 0;
    if (allf)  return 1;
    return 2;
}
__device__ __forceinline__ bool mget(const unsigned char* mp, int mode, int idx) {
    if (mode == 0) return ((const int*)mp)[idx] != 0;
    if (mode == 1) return ((const float*)mp)[idx] != 0.f;
    return mp[idx] != 0;
}

// ---------------- prep: stack + mask weights ----------------
__global__ void k_stack(const float* __restrict__ Wff1, const float* __restrict__ bff1,
                        const float* __restrict__ Wff2, const float* __restrict__ bff2,
                        const float* __restrict__ Wta,  const float* __restrict__ bta,
                        const float* __restrict__ Wtb,  const float* __restrict__ btb,
                        const unsigned char* __restrict__ maskraw,
                        int u, int c, int split,
                        float* __restrict__ outA, float* __restrict__ outB,
                        float* __restrict__ bias_out)
{
    const int mode = mask_mode(maskraw);
    const int total = 3 * u * c + 3 * u;
    for (int idx = blockIdx.x * blockDim.x + threadIdx.x; idx < total;
         idx += gridDim.x * blockDim.x) {
        if (idx < 3 * u * c) {
            int m = idx / (u * c);
            int rem = idx - m * u * c;
            int r = rem / c;
            int k = rem - r * c;
            float v;
            if (m == 2) {
                v = Wta[r * c + k] + Wtb[r * c + k];
            } else {
                bool mk = mget(maskraw, mode, r * c + k);
                float w = (m == 0) ? Wff1[r * c + k] : Wff2[r * c + k];
                v = mk ? w : 0.f;
            }
            int R = m * u + r;
            if (k < split) outA[(size_t)R * split + k] = v;
            else           outB[(size_t)R * (c - split) + (k - split)] = v;
        } else {
            int j = idx - 3 * u * c;
            int m = j / u, r = j - m * u;
            bias_out[j] = (m == 0) ? bff1[r] : ((m == 1) ? bff2[r] : (bta[r] + btb[r]));
        }
    }
}

// ---------------- prep: Wcomb = Wx0s (405x256) @ Wp (256x64) ----------------
__global__ void k_comb(const float* __restrict__ Wx0s, const float* __restrict__ Wp,
                       float* __restrict__ Wcomb)
{
    const int r = blockIdx.x;
    const int d = threadIdx.x;
    float acc = 0.f;
    for (int k = 0; k < HPn; ++k) acc += Wx0s[(size_t)r * HPn + k] * Wp[(size_t)k * DINn + d];
    Wcomb[(size_t)r * DINn + d] = acc;
}

// ---------------- prep: folded bias + Wh2 transpose ----------------
__global__ void k_biasc(const float* __restrict__ Wx0s, const float* __restrict__ bp,
                        const float* __restrict__ b0, float* __restrict__ b0c,
                        const float* __restrict__ Wh2, float* __restrict__ Wh2T)
{
    const int i = blockIdx.x * blockDim.x + threadIdx.x;
    if (i < R0c) {
        float a = b0[i];
        for (int k = 0; k < HPn; ++k) a += Wx0s[(size_t)i * HPn + k] * bp[k];
        b0c[i] = a;
    }
    if (i < HPn * 32) {
        int h = i >> 5, o = i & 31;
        Wh2T[i] = Wh2[(size_t)o * HPn + h];
    }
}

// ---------------- prep: pack weights to padded fp16 ----------------
// W0h (405,224): [Wcb:64 | Wh0s:135 | 0:25]; W1h (267,224): W1s; W2h (96,128): [W2s:121|0:7]
__global__ void k_pack(const float* __restrict__ Wcb, const float* __restrict__ Wh0s,
                       const float* __restrict__ W1s, const float* __restrict__ W2s,
                       half_t* __restrict__ W0h, half_t* __restrict__ W1h,
                       half_t* __restrict__ W2h)
{
    const int N0 = R0c * 224, N1 = R1c * 224, N2 = R2c * 128;
    for (int idx = blockIdx.x * blockDim.x + threadIdx.x; idx < N0 + N1 + N2;
         idx += gridDim.x * blockDim.x) {
        if (idx < N0) {
            int r = idx / 224, c = idx - r * 224;
            float v = (c < 64) ? Wcb[(size_t)r * 64 + c]
                               : ((c < 199) ? Wh0s[(size_t)r * 135 + (c - 64)] : 0.f);
            W0h[idx] = (half_t)v;
        } else if (idx < N0 + N1) {
            int i = idx - N0;
            W1h[i] = (half_t)W1s[i];
        } else {
            int i = idx - N0 - N1;
            int r = i / 128, c = i - r * 128;
            W2h[i] = (half_t)((c < 121) ? W2s[(size_t)r * 121 + c] : 0.f);
        }
    }
}

// ---------------- the recurrent scan: 64 blocks x 256 threads ----------------
// Quad-per-unit column-split: slot = t>>2 (64 slots), q = t&3 (column chunk).
// Every lane holds 12 weight rows x 28 half2 in registers (~336 VGPR):
//   rows 0-2: layer0 unit u0=s gates; 3-5: layer0 u1=s+64; 6-8: layer1 u=s
//   rows 9-11: s<7 -> layer0 u2=s+128 | 7<=s<39 -> layer2 u=s-7 | s>=39 -> layer1 u=s+25
// Per phase, each lane reads its 56-half z-chunk ONCE (7 ds_read_b128) and
// reuses it for all its rows; quad reduce via DPP butterfly; combine in-lane.
// Double-buffered state vectors -> 3 barriers/step, no intra-phase races.
__global__ __launch_bounds__(256, 1) void k_scan(
    const half_t* __restrict__ W0h,   // (405,224)
    const half_t* __restrict__ W1h,   // (267,224)
    const half_t* __restrict__ W2h,   // (96,128)
    const float* __restrict__ b0c,    // (405)
    const float* __restrict__ b1s,    // (267)
    const float* __restrict__ b2s,    // (96)
    const float* __restrict__ x,      // (B,T,64)
    float* __restrict__ cfc)          // (B,T,32)
{
    const int t = threadIdx.x;
    const int b = blockIdx.x;
    const int s = t >> 2;     // slot
    const int q = t & 3;      // column chunk

    __shared__ float4 z0v[2][28];   // [x:64 | h0:135 | 0:25] halfs
    __shared__ float4 z1v[2][28];   // [h0:135 | h1:89]
    __shared__ float4 z2v[2][16];   // [h1:89 | h2:32 | 0:7]

    // zero all state
    if (t < 56) { z0v[t >> 5][t & 27] = make_float4(0.f, 0.f, 0.f, 0.f); }
    {   // simpler: flat zero
        float4* zz = (float4*)z0v;
        for (int i = t; i < 56 + 56 + 32; i += 256) zz[i] = make_float4(0.f, 0.f, 0.f, 0.f);
    }

    // ---- load 12 weight rows x 28 half2 into registers ----
    half2_t w[12][28];
    {
        const half_t* rp[12];
#pragma unroll
        for (int g = 0; g < 3; ++g) {
            rp[g]     = W0h + (size_t)(s +       g * 135) * 224 + 56 * q;
            rp[3 + g] = W0h + (size_t)(s + 64 +  g * 135) * 224 + 56 * q;
            rp[6 + g] = W1h + (size_t)(s +       g * 89 ) * 224 + 56 * q;
        }
        if (s < 7) {
#pragma unroll
            for (int g = 0; g < 3; ++g)
                rp[9 + g] = W0h + (size_t)(s + 128 + g * 135) * 224 + 56 * q;
        } else if (s < 39) {
#pragma unroll
            for (int g = 0; g < 3; ++g)
                rp[9 + g] = W2h + (size_t)((s - 7) + g * 32) * 128 + 32 * q;
        } else {
#pragma unroll
            for (int g = 0; g < 3; ++g)
                rp[9 + g] = W1h + (size_t)(s + 25 + g * 89) * 224 + 56 * q;
        }
        const bool short_tail = (s >= 7 && s < 39);   // layer2 rows: only 16 half2
#pragma unroll
        for (int rb = 0; rb < 12; ++rb) {
#pragma unroll
            for (int j = 0; j < 7; ++j) {
                uint4 v = make_uint4(0u, 0u, 0u, 0u);
                if (rb < 9 || j < 4 || !short_tail) v = ((const uint4*)rp[rb])[j];
                w[rb][4 * j + 0] = __builtin_bit_cast(half2_t, v.x);
                w[rb][4 * j + 1] = __builtin_bit_cast(half2_t, v.y);
                w[rb][4 * j + 2] = __builtin_bit_cast(half2_t, v.z);
                w[rb][4 * j + 3] = __builtin_bit_cast(half2_t, v.w);
            }
        }
    }

    // ---- per-lane combine-unit assignment + biases ----
    const bool cA = (q < 2) || (q == 2 && s < 7);
    const int uAc = (q == 0) ? s : ((q == 1) ? s + 64 : ((q == 2 && s < 7) ? s + 128 : 0));
    const float bA0 = b0c[uAc], bA1 = b0c[uAc + 135], bA2 = b0c[uAc + 270];

    const bool cB = (q == 0) || (q == 1 && s >= 39);
    const int uBc = (q == 0) ? s : ((q == 1 && s >= 39) ? s + 25 : 0);
    const float bB0 = b1s[uBc], bB1 = b1s[uBc + 89], bB2 = b1s[uBc + 178];

    const bool cC = (q == 0) && (s >= 7) && (s < 39);
    const int uCc = cC ? (s - 7) : 0;
    const float bC0 = b2s[uCc], bC1 = b2s[uCc + 32], bC2 = b2s[uCc + 64];

    const float* xb = x + (size_t)b * TTs * DINn;
    float* cfb = cfc + (size_t)b * TTs * 32;
    const int xi = t - 128;                       // wave 2 stages x
    const bool xw = (xi >= 0 && xi < 64);

    __syncthreads();
    if (xw) ((half_t*)&z0v[0][0])[xi] = (half_t)xb[xi];   // x(0)
    __syncthreads();

#pragma unroll 1
    for (int ts = 0; ts < TTs; ++ts) {
        const int p = ts & 1;
        half_t* z0n = (half_t*)&z0v[1 - p][0];
        half_t* z1c = (half_t*)&z1v[p][0];
        half_t* z1n = (half_t*)&z1v[1 - p][0];
        half_t* z2c = (half_t*)&z2v[p][0];
        half_t* z2n = (half_t*)&z2v[1 - p][0];

        // prefetch x(ts+1) (consumed end of phase C)
        float xnext = 0.f;
        if (xw) {
            int tn = (ts + 1 < TTs) ? ts + 1 : ts;
            xnext = xb[(size_t)tn * DINn + xi];
        }

        float acc[9];
#pragma unroll
        for (int r = 0; r < 9; ++r) acc[r] = 0.f;

        // ================= phase A : layer0 over z0=[x|h0] =================
        {
            const float4* zc = &z0v[p][q * 7];
#pragma unroll
            for (int j = 0; j < 7; ++j) {
                float4 f = zc[j];
                half2_t v0 = __builtin_bit_cast(half2_t, f.x);
                half2_t v1 = __builtin_bit_cast(half2_t, f.y);
                half2_t v2 = __builtin_bit_cast(half2_t, f.z);
                half2_t v3 = __builtin_bit_cast(half2_t, f.w);
#pragma unroll
                for (int r = 0; r < 6; ++r) {
                    acc[r] = __builtin_amdgcn_fdot2(w[r][4 * j + 0], v0, acc[r], false);
                    acc[r] = __builtin_amdgcn_fdot2(w[r][4 * j + 1], v1, acc[r], false);
                    acc[r] = __builtin_amdgcn_fdot2(w[r][4 * j + 2], v2, acc[r], false);
                    acc[r] = __builtin_amdgcn_fdot2(w[r][4 * j + 3], v3, acc[r], false);
                }
                if (s < 7) {   // layer0 extra unit (wave 0 only)
#pragma unroll
                    for (int r = 6; r < 9; ++r) {
                        acc[r] = __builtin_amdgcn_fdot2(w[r + 3][4 * j + 0], v0, acc[r], false);
                        acc[r] = __builtin_amdgcn_fdot2(w[r + 3][4 * j + 1], v1, acc[r], false);
                        acc[r] = __builtin_amdgcn_fdot2(w[r + 3][4 * j + 2], v2, acc[r], false);
                        acc[r] = __builtin_amdgcn_fdot2(w[r + 3][4 * j + 3], v3, acc[r], false);
                    }
                }
            }
            float r0 = qsum(acc[0]), r1 = qsum(acc[1]), r2 = qsum(acc[2]);
            float r3 = qsum(acc[3]), r4 = qsum(acc[4]), r5 = qsum(acc[5]);
            float r6 = 0.f, r7 = 0.f, r8 = 0.f;
            if (s < 7) { r6 = qsum(acc[6]); r7 = qsum(acc[7]); r8 = qsum(acc[8]); }
            if (cA) {
                float y0 = ((q == 0) ? r0 : (q == 1) ? r3 : r6) + bA0;
                float y1 = ((q == 0) ? r1 : (q == 1) ? r4 : r7) + bA1;
                float y2 = ((q == 0) ? r2 : (q == 1) ? r5 : r8) + bA2;
                float f1 = tanh_f(y0), f2 = tanh_f(y1), ti = sigm_f(y2);
                float hn = f1 + ti * (f2 - f1);
                half_t hh = (half_t)hn;
                z0n[64 + uAc] = hh;   // for next step's phase A
                z1c[uAc]      = hh;   // for this step's phase B
            }
        }
        __syncthreads();

        // ================= phase B : layer1 over z1=[h0|h1] =================
        {
#pragma unroll
            for (int r = 0; r < 6; ++r) acc[r] = 0.f;
            const float4* zc = &z1v[p][q * 7];
#pragma unroll
            for (int j = 0; j < 7; ++j) {
                float4 f = zc[j];
                half2_t v0 = __builtin_bit_cast(half2_t, f.x);
                half2_t v1 = __builtin_bit_cast(half2_t, f.y);
                half2_t v2 = __builtin_bit_cast(half2_t, f.z);
                half2_t v3 = __builtin_bit_cast(half2_t, f.w);
#pragma unroll
                for (int r = 0; r < 3; ++r) {
                    acc[r] = __builtin_amdgcn_fdot2(w[6 + r][4 * j + 0], v0, acc[r], false);
                    acc[r] = __builtin_amdgcn_fdot2(w[6 + r][4 * j + 1], v1, acc[r], false);
                    acc[r] = __builtin_amdgcn_fdot2(w[6 + r][4 * j + 2], v2, acc[r], false);
                    acc[r] = __builtin_amdgcn_fdot2(w[6 + r][4 * j + 3], v3, acc[r], false);
                }
                if (s >= 39) {   // second layer1 unit (waves 2-3)
#pragma unroll
                    for (int r = 3; r < 6; ++r) {
                        acc[r] = __builtin_amdgcn_fdot2(w[6 + r][4 * j + 0], v0, acc[r], false);
                        acc[r] = __builtin_amdgcn_fdot2(w[6 + r][4 * j + 1], v1, acc[r], false);
                        acc[r] = __builtin_amdgcn_fdot2(w[6 + r][4 * j + 2], v2, acc[r], false);
                        acc[r] = __builtin_amdgcn_fdot2(w[6 + r][4 * j + 3], v3, acc[r], false);
                    }
                }
            }
            float r0 = qsum(acc[0]), r1 = qsum(acc[1]), r2 = qsum(acc[2]);
            float r3 = 0.f, r4 = 0.f, r5 = 0.f;
            if (s >= 39) { r3 = qsum(acc[3]); r4 = qsum(acc[4]); r5 = qsum(acc[5]); }
            if (cB) {
                float y0 = ((q == 0) ? r0 : r3) + bB0;
                float y1 = ((q == 0) ? r1 : r4) + bB1;
                float y2 = ((q == 0) ? r2 : r5) + bB2;
                float f1 = tanh_f(y0), f2 = tanh_f(y1), ti = sigm_f(y2);
                float hn = f1 + ti * (f2 - f1);
                half_t hh = (half_t)hn;
                z1n[135 + uBc] = hh;   // next step's phase B
                z2c[uBc]       = hh;   // this step's phase C
            }
        }
        __syncthreads();

        // ================= phase C : layer2 over z2=[h1|h2] =================
        if (s >= 7 && s < 39) {
            float a0 = 0.f, a1 = 0.f, a2 = 0.f;
            const float4* zc = &z2v[p][q * 4];
#pragma unroll
            for (int j = 0; j < 4; ++j) {
                float4 f = zc[j];
                half2_t v0 = __builtin_bit_cast(half2_t, f.x);
                half2_t v1 = __builtin_bit_cast(half2_t, f.y);
                half2_t v2 = __builtin_bit_cast(half2_t, f.z);
                half2_t v3 = __builtin_bit_cast(half2_t, f.w);
                a0 = __builtin_amdgcn_fdot2(w[9][4 * j + 0], v0, a0, false);
                a0 = __builtin_amdgcn_fdot2(w[9][4 * j + 1], v1, a0, false);
                a0 = __builtin_amdgcn_fdot2(w[9][4 * j + 2], v2, a0, false);
                a0 = __builtin_amdgcn_fdot2(w[9][4 * j + 3], v3, a0, false);
                a1 = __builtin_amdgcn_fdot2(w[10][4 * j + 0], v0, a1, false);
                a1 = __builtin_amdgcn_fdot2(w[10][4 * j + 1], v1, a1, false);
                a1 = __builtin_amdgcn_fdot2(w[10][4 * j + 2], v2, a1, false);
                a1 = __builtin_amdgcn_fdot2(w[10][4 * j + 3], v3, a1, false);
                a2 = __builtin_amdgcn_fdot2(w[11][4 * j + 0], v0, a2, false);
                a2 = __builtin_amdgcn_fdot2(w[11][4 * j + 1], v1, a2, false);
                a2 = __builtin_amdgcn_fdot2(w[11][4 * j + 2], v2, a2, false);
                a2 = __builtin_amdgcn_fdot2(w[11][4 * j + 3], v3, a2, false);
            }
            float r0 = qsum(a0), r1 = qsum(a1), r2 = qsum(a2);
            if (cC) {
                float f1 = tanh_f(r0 + bC0), f2 = tanh_f(r1 + bC1), ti = sigm_f(r2 + bC2);
                float hn = f1 + ti * (f2 - f1);
                z2n[89 + uCc] = (half_t)hn;
                cfb[(size_t)ts * 32 + uCc] = hn;
            }
        }
        if (xw) z0n[xi] = (half_t)xnext;   // x(ts+1)
        __syncthreads();
    }
}

// ---------------- head: in-place gelu(cfc@Wh1.T+bh1)@Wh2.T + bh2 ----------------
__global__ __launch_bounds__(256) void k_head(float* io,
                                              const float* __restrict__ Wh1,
                                              const float* __restrict__ bh1,
                                              const float* __restrict__ Wh2T,
                                              const float* __restrict__ bh2)
{
    const int bt = blockIdx.x * 256 + threadIdx.x;
    float c32[32];
    const float4* cp = (const float4*)(io + (size_t)bt * 32);
#pragma unroll
    for (int k = 0; k < 8; ++k) {
        float4 v = cp[k];
        c32[4 * k] = v.x; c32[4 * k + 1] = v.y; c32[4 * k + 2] = v.z; c32[4 * k + 3] = v.w;
    }
    float acc[32];
#pragma unroll
    for (int o = 0; o < 32; ++o) acc[o] = bh2[o];
#pragma unroll 1
    for (int h = 0; h < HPn; ++h) {
        float ss = bh1[h];
        const float* w1r = Wh1 + (size_t)h * 32;
#pragma unroll
        for (int k = 0; k < 32; ++k) ss += c32[k] * w1r[k];
        float g = 0.5f * ss * (1.f + erff(ss * 0.70710678118654752440f));
        const float* w2r = Wh2T + (size_t)h * 32;
#pragma unroll
        for (int o = 0; o < 32; ++o) acc[o] += g * w2r[o];
    }
    float4* op = (float4*)(io + (size_t)bt * 32);
#pragma unroll
    for (int k = 0; k < 8; ++k) {
        float4 v;
        v.x = acc[4 * k]; v.y = acc[4 * k + 1]; v.z = acc[4 * k + 2]; v.w = acc[4 * k + 3];
        op[k] = v;
    }
}

// ---------------- launch ----------------
extern "C" void kernel_launch(void* const* d_in, const int* in_sizes, int n_in,
                              void* d_out, int out_size, void* d_ws, size_t ws_size,
                              hipStream_t stream)
{
    (void)in_sizes; (void)n_in; (void)out_size; (void)ws_size;
    const float* x      = (const float*)d_in[0];
    const float* Wp     = (const float*)d_in[1];
    const float* bp     = (const float*)d_in[2];
    const float* Wff1_0 = (const float*)d_in[3];
    const float* bff1_0 = (const float*)d_in[4];
    const float* Wff2_0 = (const float*)d_in[5];
    const float* bff2_0 = (const float*)d_in[6];
    const float* Wta_0  = (const float*)d_in[7];
    const float* bta_0  = (const float*)d_in[8];
    const float* Wtb_0  = (const float*)d_in[9];
    const float* btb_0  = (const float*)d_in[10];
    const unsigned char* mask_0 = (const unsigned char*)d_in[11];
    const float* Wff1_1 = (const float*)d_in[12];
    const float* bff1_1 = (const float*)d_in[13];
    const float* Wff2_1 = (const float*)d_in[14];
    const float* bff2_1 = (const float*)d_in[15];
    const float* Wta_1  = (const float*)d_in[16];
    const float* bta_1  = (const float*)d_in[17];
    const float* Wtb_1  = (const float*)d_in[18];
    const float* btb_1  = (const float*)d_in[19];
    const unsigned char* mask_1 = (const unsigned char*)d_in[20];
    const float* Wff1_2 = (const float*)d_in[21];
    const float* bff1_2 = (const float*)d_in[22];
    const float* Wff2_2 = (const float*)d_in[23];
    const float* bff2_2 = (const float*)d_in[24];
    const float* Wta_2  = (const float*)d_in[25];
    const float* bta_2  = (const float*)d_in[26];
    const float* Wtb_2  = (const float*)d_in[27];
    const float* btb_2  = (const float*)d_in[28];
    const unsigned char* mask_2 = (const unsigned char*)d_in[29];
    const float* Wh1    = (const float*)d_in[30];
    const float* bh1    = (const float*)d_in[31];
    const float* Wh2    = (const float*)d_in[32];
    const float* bh2    = (const float*)d_in[33];

    float* ws = (float*)d_ws;
    size_t o = 0;
    float* Wh0s = ws + o; o += (size_t)R0c * U0c;
    float* Wx0s = ws + o; o += (size_t)R0c * HPn;
    float* b0s  = ws + o; o += R0c; o += 3;          // pad to keep 16B alignment
    float* Wcb  = ws + o; o += (size_t)R0c * DINn;
    float* b0c  = ws + o; o += R0c; o += 3;
    float* W1s  = ws + o; o += (size_t)R1c * C1c;
    float* b1s  = ws + o; o += R1c; o += 1;
    float* W2s  = ws + o; o += (size_t)R2c * C2c;
    float* b2s  = ws + o; o += R2c;
    float* Wh2T = ws + o; o += (size_t)HPn * 32;
    half_t* W0h = (half_t*)(ws + o); o += (size_t)R0c * 224 / 2;   // 224-col half rows
    half_t* W1h = (half_t*)(ws + o); o += (size_t)R1c * 224 / 2;
    half_t* W2h = (half_t*)(ws + o); o += (size_t)R2c * 128 / 2;

    k_stack<<<128, 256, 0, stream>>>(Wff1_0, bff1_0, Wff2_0, bff2_0, Wta_0, bta_0, Wtb_0, btb_0,
                                     mask_0, U0c, C0c, HPn, Wx0s, Wh0s, b0s);
    k_stack<<<64, 256, 0, stream>>>(Wff1_1, bff1_1, Wff2_1, bff2_1, Wta_1, bta_1, Wtb_1, btb_1,
                                    mask_1, U1c, C1c, C1c, W1s, W1s, b1s);
    k_stack<<<16, 256, 0, stream>>>(Wff1_2, bff1_2, Wff2_2, bff2_2, Wta_2, bta_2, Wtb_2, btb_2,
                                    mask_2, U2c, C2c, C2c, W2s, W2s, b2s);
    k_comb<<<R0c, DINn, 0, stream>>>(Wx0s, Wp, Wcb);
    k_biasc<<<32, 256, 0, stream>>>(Wx0s, bp, b0s, b0c, Wh2, Wh2T);
    k_pack<<<320, 256, 0, stream>>>(Wcb, Wh0s, W1s, W2s, W0h, W1h, W2h);
    k_scan<<<BBn, 256, 0, stream>>>(W0h, W1h, W2h, b0c, b1s, b2s, x, (float*)d_out);
    k_head<<<(int)(BTn / 256), 256, 0, stream>>>((float*)d_out, Wh1, bh1, Wh2T, bh2);
}

// Round 4
// 4830.375 us; speedup vs baseline: 1.0417x; 1.0417x over previous
//
#include <hip/hip_runtime.h>
#include <cstdint>
#include <cstddef>

typedef _Float16 half_t;
typedef half_t half2_t __attribute__((ext_vector_type(2)));

static constexpr int TTs = 2048;   // timesteps
static constexpr int BBn = 64;     // batch
static constexpr int DINn = 64;    // input dim
static constexpr int HPn  = 256;   // proj dim
static constexpr int U0c = 135, C0c = 391, R0c = 405;   // layer0
static constexpr int U1c = 89,  C1c = 224, R1c = 267;   // layer1
static constexpr int U2c = 32,  C2c = 121, R2c = 96;    // layer2
static constexpr size_t BTn = (size_t)BBn * TTs;        // 131072

// ---------------- math helpers ----------------
__device__ __forceinline__ float tanh_f(float x) {
    return 1.f - __fdividef(2.f, __expf(2.f * x) + 1.f);
}
__device__ __forceinline__ float sigm_f(float x) {
    return __fdividef(1.f, 1.f + __expf(-x));
}
// quad butterfly sum via DPP (VALU pipe, no LDS)
__device__ __forceinline__ float qsum(float v) {
    v += __builtin_bit_cast(float, __builtin_amdgcn_update_dpp(
             0, __builtin_bit_cast(int, v), 0xB1, 0xF, 0xF, true));  // [1,0,3,2]
    v += __builtin_bit_cast(float, __builtin_amdgcn_update_dpp(
             0, __builtin_bit_cast(int, v), 0x4E, 0xF, 0xF, true));  // [2,3,0,1]
    return v;
}
__device__ __forceinline__ half2_t h2(unsigned u) { return __builtin_bit_cast(half2_t, u); }

// ---------------- mask dtype probe ----------------
__device__ __forceinline__ int mask_mode(const unsigned char* mp) {
    const unsigned* wp = (const unsigned*)mp;
    bool all01 = true, allf = true;
    for (int k = 0; k < 64; ++k) {
        unsigned w = wp[k];
        all01 = all01 && (w == 0u || w == 1u);
        allf  = allf  && (w == 0u || w == 0x3F800000u);
    }
    if (all01) return 0;
    if (allf)  return 1;
    return 2;
}
__device__ __forceinline__ bool mget(const unsigned char* mp, int mode, int idx) {
    if (mode == 0) return ((const int*)mp)[idx] != 0;
    if (mode == 1) return ((const float*)mp)[idx] != 0.f;
    return mp[idx] != 0;
}

// ---------------- prep: stack + mask weights ----------------
__global__ void k_stack(const float* __restrict__ Wff1, const float* __restrict__ bff1,
                        const float* __restrict__ Wff2, const float* __restrict__ bff2,
                        const float* __restrict__ Wta,  const float* __restrict__ bta,
                        const float* __restrict__ Wtb,  const float* __restrict__ btb,
                        const unsigned char* __restrict__ maskraw,
                        int u, int c, int split,
                        float* __restrict__ outA, float* __restrict__ outB,
                        float* __restrict__ bias_out)
{
    const int mode = mask_mode(maskraw);
    const int total = 3 * u * c + 3 * u;
    for (int idx = blockIdx.x * blockDim.x + threadIdx.x; idx < total;
         idx += gridDim.x * blockDim.x) {
        if (idx < 3 * u * c) {
            int m = idx / (u * c);
            int rem = idx - m * u * c;
            int r = rem / c;
            int k = rem - r * c;
            float v;
            if (m == 2) {
                v = Wta[r * c + k] + Wtb[r * c + k];
            } else {
                bool mk = mget(maskraw, mode, r * c + k);
                float w = (m == 0) ? Wff1[r * c + k] : Wff2[r * c + k];
                v = mk ? w : 0.f;
            }
            int R = m * u + r;
            if (k < split) outA[(size_t)R * split + k] = v;
            else           outB[(size_t)R * (c - split) + (k - split)] = v;
        } else {
            int j = idx - 3 * u * c;
            int m = j / u, r = j - m * u;
            bias_out[j] = (m == 0) ? bff1[r] : ((m == 1) ? bff2[r] : (bta[r] + btb[r]));
        }
    }
}

// ---------------- prep: Wcomb = Wx0s (405x256) @ Wp (256x64) ----------------
__global__ void k_comb(const float* __restrict__ Wx0s, const float* __restrict__ Wp,
                       float* __restrict__ Wcomb)
{
    const int r = blockIdx.x;
    const int d = threadIdx.x;
    float acc = 0.f;
    for (int k = 0; k < HPn; ++k) acc += Wx0s[(size_t)r * HPn + k] * Wp[(size_t)k * DINn + d];
    Wcomb[(size_t)r * DINn + d] = acc;
}

// ---------------- prep: folded bias + Wh2 transpose ----------------
__global__ void k_biasc(const float* __restrict__ Wx0s, const float* __restrict__ bp,
                        const float* __restrict__ b0, float* __restrict__ b0c,
                        const float* __restrict__ Wh2, float* __restrict__ Wh2T)
{
    const int i = blockIdx.x * blockDim.x + threadIdx.x;
    if (i < R0c) {
        float a = b0[i];
        for (int k = 0; k < HPn; ++k) a += Wx0s[(size_t)i * HPn + k] * bp[k];
        b0c[i] = a;
    }
    if (i < HPn * 32) {
        int h = i >> 5, o = i & 31;
        Wh2T[i] = Wh2[(size_t)o * HPn + h];
    }
}

// ---------------- prep: pack weights to padded fp16 ----------------
// W0h (405,224): [Wcb:64 | Wh0s:135 | 0:25]; W1h (267,224); W2h (96,128): [W2s:121|0:7]
__global__ void k_pack(const float* __restrict__ Wcb, const float* __restrict__ Wh0s,
                       const float* __restrict__ W1s, const float* __restrict__ W2s,
                       half_t* __restrict__ W0h, half_t* __restrict__ W1h,
                       half_t* __restrict__ W2h)
{
    const int N0 = R0c * 224, N1 = R1c * 224, N2 = R2c * 128;
    for (int idx = blockIdx.x * blockDim.x + threadIdx.x; idx < N0 + N1 + N2;
         idx += gridDim.x * blockDim.x) {
        if (idx < N0) {
            int r = idx / 224, c = idx - r * 224;
            float v = (c < 64) ? Wcb[(size_t)r * 64 + c]
                               : ((c < 199) ? Wh0s[(size_t)r * 135 + (c - 64)] : 0.f);
            W0h[idx] = (half_t)v;
        } else if (idx < N0 + N1) {
            int i = idx - N0;
            W1h[i] = (half_t)W1s[i];
        } else {
            int i = idx - N0 - N1;
            int r = i / 128, c = i - r * 128;
            W2h[i] = (half_t)((c < 121) ? W2s[(size_t)r * 121 + c] : 0.f);
        }
    }
}

// ---------------- the recurrent scan: 64 blocks x 512 threads ----------------
// Quad-per-unit column-split (slot = t>>2 in 0..127, q = t&3 = 56-half chunk).
// wA[84]: layer0 unit u=s (3 gate rows x 28 half2) -- all lanes.
// wX[96]: role-shared by wave: wave0 = 21 leftover layer0 rows (2x28);
//         waves1..6 = one layer1 unit (3x28); wave7 = two layer2 units (6x16).
// asm "+v" KEEP forces the weights to stay VGPR-resident across the loop.
// In-lane combine after DPP qsum -> 3 barriers/step, double-buffered state.
__global__ __launch_bounds__(512, 2) void k_scan(
    const half_t* __restrict__ W0h,   // (405,224)
    const half_t* __restrict__ W1h,   // (267,224)
    const half_t* __restrict__ W2h,   // (96,128)
    const float* __restrict__ b0c,    // (405)
    const float* __restrict__ b1s,    // (267)
    const float* __restrict__ b2s,    // (96)
    const float* __restrict__ x,      // (B,T,64)
    float* __restrict__ cfc)          // (B,T,32)
{
    const int t = threadIdx.x;
    const int b = blockIdx.x;
    const int s = t >> 2;     // slot 0..127
    const int q = t & 3;      // column chunk
    const int wid = t >> 6;   // wave 0..7

    __shared__ float4 z0v[2][28];   // 224 halfs: [x:64 | h0:135 | 0:25]
    __shared__ float4 z1v[2][28];   // 224 halfs: [h0:135 | h1:89]
    __shared__ float4 z2v[2][16];   // 128 halfs: [h1:89 | h2:32 | 0:7]
    __shared__ float  ybuf[24];     // wave0 leftover row sums

    if (t < 56) ((float4*)z0v)[t] = make_float4(0.f, 0.f, 0.f, 0.f);
    if (t < 56) ((float4*)z1v)[t] = make_float4(0.f, 0.f, 0.f, 0.f);
    if (t < 32) ((float4*)z2v)[t] = make_float4(0.f, 0.f, 0.f, 0.f);

    // ---- load weights: wA = layer0 unit s (rows s, 135+s, 270+s), chunk q ----
    unsigned wA[84];
    {
        const uint4* r0 = (const uint4*)(W0h + (size_t)s         * 224 + 56 * q);
        const uint4* r1 = (const uint4*)(W0h + (size_t)(135 + s) * 224 + 56 * q);
        const uint4* r2 = (const uint4*)(W0h + (size_t)(270 + s) * 224 + 56 * q);
#pragma unroll
        for (int j = 0; j < 7; ++j) {
            uint4 v0 = r0[j], v1 = r1[j], v2 = r2[j];
            wA[      4 * j + 0] = v0.x; wA[      4 * j + 1] = v0.y;
            wA[      4 * j + 2] = v0.z; wA[      4 * j + 3] = v0.w;
            wA[28 +  4 * j + 0] = v1.x; wA[28 +  4 * j + 1] = v1.y;
            wA[28 +  4 * j + 2] = v1.z; wA[28 +  4 * j + 3] = v1.w;
            wA[56 +  4 * j + 0] = v2.x; wA[56 +  4 * j + 1] = v2.y;
            wA[56 +  4 * j + 2] = v2.z; wA[56 +  4 * j + 3] = v2.w;
        }
    }
    // ---- role-shared wX ----
    unsigned wX[96];
#pragma unroll
    for (int i = 0; i < 96; ++i) wX[i] = 0u;
    if (wid == 0) {
        // leftover layer0 rows, index i -> row: i<7:128+i | i<14:263+(i-7) | 398+(i-14)
        int i0 = s;                                   // 0..15 (<21 always)
        int r0i = (i0 < 7) ? 128 + i0 : (i0 < 14) ? 263 + (i0 - 7) : 398 + (i0 - 14);
        const uint4* p0 = (const uint4*)(W0h + (size_t)r0i * 224 + 56 * q);
        bool ok1 = (s < 5);
        int r1i = ok1 ? (400 + s) : r0i;              // i1=16+s -> 398+(i1-14)
        const uint4* p1 = (const uint4*)(W0h + (size_t)r1i * 224 + 56 * q);
#pragma unroll
        for (int j = 0; j < 7; ++j) {
            uint4 v0 = p0[j];
            wX[4 * j + 0] = v0.x; wX[4 * j + 1] = v0.y;
            wX[4 * j + 2] = v0.z; wX[4 * j + 3] = v0.w;
            uint4 v1 = p1[j];
            wX[28 + 4 * j + 0] = ok1 ? v1.x : 0u; wX[28 + 4 * j + 1] = ok1 ? v1.y : 0u;
            wX[28 + 4 * j + 2] = ok1 ? v1.z : 0u; wX[28 + 4 * j + 3] = ok1 ? v1.w : 0u;
        }
    } else if (wid <= 6) {
        int u = s - 16;                               // 0..95
        bool ok = (u < U1c);
        int uu = ok ? u : 0;
        const uint4* r0 = (const uint4*)(W1h + (size_t)uu          * 224 + 56 * q);
        const uint4* r1 = (const uint4*)(W1h + (size_t)(89 + uu)   * 224 + 56 * q);
        const uint4* r2 = (const uint4*)(W1h + (size_t)(178 + uu)  * 224 + 56 * q);
#pragma unroll
        for (int j = 0; j < 7; ++j) {
            uint4 v0 = r0[j], v1 = r1[j], v2 = r2[j];
            wX[      4 * j + 0] = ok ? v0.x : 0u; wX[      4 * j + 1] = ok ? v0.y : 0u;
            wX[      4 * j + 2] = ok ? v0.z : 0u; wX[      4 * j + 3] = ok ? v0.w : 0u;
            wX[28 +  4 * j + 0] = ok ? v1.x : 0u; wX[28 +  4 * j + 1] = ok ? v1.y : 0u;
            wX[28 +  4 * j + 2] = ok ? v1.z : 0u; wX[28 +  4 * j + 3] = ok ? v1.w : 0u;
            wX[56 +  4 * j + 0] = ok ? v2.x : 0u; wX[56 +  4 * j + 1] = ok ? v2.y : 0u;
            wX[56 +  4 * j + 2] = ok ? v2.z : 0u; wX[56 +  4 * j + 3] = ok ? v2.w : 0u;
        }
    } else {
        int u0 = 2 * (s - 112);                       // 0,2,..,30
        const uint4* rp[6];
        rp[0] = (const uint4*)(W2h + (size_t)(u0)      * 128 + 32 * q);
        rp[1] = (const uint4*)(W2h + (size_t)(32 + u0) * 128 + 32 * q);
        rp[2] = (const uint4*)(W2h + (size_t)(64 + u0) * 128 + 32 * q);
        rp[3] = (const uint4*)(W2h + (size_t)(u0 + 1)  * 128 + 32 * q);
        rp[4] = (const uint4*)(W2h + (size_t)(33 + u0) * 128 + 32 * q);
        rp[5] = (const uint4*)(W2h + (size_t)(65 + u0) * 128 + 32 * q);
#pragma unroll
        for (int r = 0; r < 6; ++r) {
#pragma unroll
            for (int j = 0; j < 4; ++j) {
                uint4 v = rp[r][j];
                wX[16 * r + 4 * j + 0] = v.x; wX[16 * r + 4 * j + 1] = v.y;
                wX[16 * r + 4 * j + 2] = v.z; wX[16 * r + 4 * j + 3] = v.w;
            }
        }
    }
    // ---- force VGPR residency (opaque defs: not rematerializable) ----
#pragma unroll
    for (int i = 0; i < 84; ++i) asm volatile("" : "+v"(wA[i]));
#pragma unroll
    for (int i = 0; i < 96; ++i) asm volatile("" : "+v"(wX[i]));

    // ---- biases ----
    const float bA0 = b0c[s], bA1 = b0c[135 + s], bA2 = b0c[270 + s];
    float bL0 = 0.f, bL1 = 0.f, bL2 = 0.f;            // wave0 lanes t<7
    if (t < 7) { bL0 = b0c[128 + t]; bL1 = b0c[263 + t]; bL2 = b0c[398 + t]; }
    float bR0 = 0.f, bR1 = 0.f, bR2 = 0.f, bR3 = 0.f, bR4 = 0.f, bR5 = 0.f;
    if (wid >= 1 && wid <= 6) {
        int u = s - 16; int uu = (u < U1c) ? u : 0;
        bR0 = b1s[uu]; bR1 = b1s[89 + uu]; bR2 = b1s[178 + uu];
    } else if (wid == 7) {
        int u0 = 2 * (s - 112);
        bR0 = b2s[u0];     bR1 = b2s[32 + u0]; bR2 = b2s[64 + u0];
        bR3 = b2s[u0 + 1]; bR4 = b2s[33 + u0]; bR5 = b2s[65 + u0];
    }

    const float* xb = x + (size_t)b * TTs * DINn;
    float* cfb = cfc + (size_t)b * TTs * 32;

    __syncthreads();
    if (t < 64) ((half_t*)&z0v[0][0])[t] = (half_t)xb[t];   // x(0)
    __syncthreads();

#define DOT4(acc, arr, base) \
    acc = __builtin_amdgcn_fdot2(h2(arr[(base) + 0]), v0, acc, false); \
    acc = __builtin_amdgcn_fdot2(h2(arr[(base) + 1]), v1, acc, false); \
    acc = __builtin_amdgcn_fdot2(h2(arr[(base) + 2]), v2, acc, false); \
    acc = __builtin_amdgcn_fdot2(h2(arr[(base) + 3]), v3, acc, false);

#pragma unroll 1
    for (int ts = 0; ts < TTs; ++ts) {
        const int p = ts & 1;
        half_t* z0n = (half_t*)&z0v[p ^ 1][0];
        half_t* z1c = (half_t*)&z1v[p][0];
        half_t* z1n = (half_t*)&z1v[p ^ 1][0];
        half_t* z2c = (half_t*)&z2v[p][0];
        half_t* z2n = (half_t*)&z2v[p ^ 1][0];

        float xnext = 0.f;
        if (t < 64) {
            int tn = (ts + 1 < TTs) ? ts + 1 : ts;
            xnext = xb[(size_t)tn * DINn + t];
        }

        // ================= phase A : layer0 over z0=[x|h0] =================
        {
            const float4* zc = &z0v[p][q * 7];
            float a0 = 0.f, a1 = 0.f, a2 = 0.f, a3 = 0.f, a4 = 0.f;
#pragma unroll
            for (int j = 0; j < 7; ++j) {
                float4 f = zc[j];
                half2_t v0 = __builtin_bit_cast(half2_t, f.x);
                half2_t v1 = __builtin_bit_cast(half2_t, f.y);
                half2_t v2 = __builtin_bit_cast(half2_t, f.z);
                half2_t v3 = __builtin_bit_cast(half2_t, f.w);
                DOT4(a0, wA, 4 * j)
                DOT4(a1, wA, 28 + 4 * j)
                DOT4(a2, wA, 56 + 4 * j)
                if (wid == 0) {
                    DOT4(a3, wX, 4 * j)
                    DOT4(a4, wX, 28 + 4 * j)
                }
            }
            a0 = qsum(a0); a1 = qsum(a1); a2 = qsum(a2);
            if (q == 0) {
                float f1 = tanh_f(a0 + bA0), f2 = tanh_f(a1 + bA1), ti = sigm_f(a2 + bA2);
                float hn = f1 + ti * (f2 - f1);
                half_t hh = (half_t)hn;
                z1c[s]      = hh;
                z0n[64 + s] = hh;
            }
            if (wid == 0) {
                a3 = qsum(a3); a4 = qsum(a4);
                if (q == 0) {
                    ybuf[s] = a3;
                    if (s < 5) ybuf[16 + s] = a4;
                }
                asm volatile("s_waitcnt lgkmcnt(0)" ::: "memory");
                if (t < 7) {   // combine leftover units 128..134 (same wave: no barrier)
                    float y0 = ybuf[t] + bL0;
                    float y1 = ybuf[7 + t] + bL1;
                    float y2 = ybuf[14 + t] + bL2;
                    float f1 = tanh_f(y0), f2 = tanh_f(y1), ti = sigm_f(y2);
                    float hn = f1 + ti * (f2 - f1);
                    half_t hh = (half_t)hn;
                    z1c[128 + t]      = hh;
                    z0n[192 + t]      = hh;   // 64 + 128 + t
                }
            }
        }
        __syncthreads();

        // ================= phase B : layer1 over z1=[h0|h1] (waves 1..6) ====
        if (wid >= 1 && wid <= 6) {
            const float4* zc = &z1v[p][q * 7];
            float a0 = 0.f, a1 = 0.f, a2 = 0.f;
#pragma unroll
            for (int j = 0; j < 7; ++j) {
                float4 f = zc[j];
                half2_t v0 = __builtin_bit_cast(half2_t, f.x);
                half2_t v1 = __builtin_bit_cast(half2_t, f.y);
                half2_t v2 = __builtin_bit_cast(half2_t, f.z);
                half2_t v3 = __builtin_bit_cast(half2_t, f.w);
                DOT4(a0, wX, 4 * j)
                DOT4(a1, wX, 28 + 4 * j)
                DOT4(a2, wX, 56 + 4 * j)
            }
            a0 = qsum(a0); a1 = qsum(a1); a2 = qsum(a2);
            int u = s - 16;
            if (q == 0 && u < U1c) {
                float f1 = tanh_f(a0 + bR0), f2 = tanh_f(a1 + bR1), ti = sigm_f(a2 + bR2);
                float hn = f1 + ti * (f2 - f1);
                half_t hh = (half_t)hn;
                z2c[u]       = hh;
                z1n[135 + u] = hh;
            }
        }
        __syncthreads();

        // ================= phase C : layer2 over z2=[h1|h2] (wave 7) ========
        if (wid == 7) {
            const float4* zc = &z2v[p][q * 4];
            float a0 = 0.f, a1 = 0.f, a2 = 0.f, a3 = 0.f, a4 = 0.f, a5 = 0.f;
#pragma unroll
            for (int j = 0; j < 4; ++j) {
                float4 f = zc[j];
                half2_t v0 = __builtin_bit_cast(half2_t, f.x);
                half2_t v1 = __builtin_bit_cast(half2_t, f.y);
                half2_t v2 = __builtin_bit_cast(half2_t, f.z);
                half2_t v3 = __builtin_bit_cast(half2_t, f.w);
                DOT4(a0, wX, 4 * j)
                DOT4(a1, wX, 16 + 4 * j)
                DOT4(a2, wX, 32 + 4 * j)
                DOT4(a3, wX, 48 + 4 * j)
                DOT4(a4, wX, 64 + 4 * j)
                DOT4(a5, wX, 80 + 4 * j)
            }
            a0 = qsum(a0); a1 = qsum(a1); a2 = qsum(a2);
            a3 = qsum(a3); a4 = qsum(a4); a5 = qsum(a5);
            if (q == 0) {
                int u0 = 2 * (s - 112);
                float f1 = tanh_f(a0 + bR0), f2 = tanh_f(a1 + bR1), ti = sigm_f(a2 + bR2);
                float hn0 = f1 + ti * (f2 - f1);
                z2n[89 + u0] = (half_t)hn0;
                cfb[(size_t)ts * 32 + u0] = hn0;
                float g1 = tanh_f(a3 + bR3), g2 = tanh_f(a4 + bR4), tj = sigm_f(a5 + bR5);
                float hn1 = g1 + tj * (g2 - g1);
                z2n[89 + u0 + 1] = (half_t)hn1;
                cfb[(size_t)ts * 32 + u0 + 1] = hn1;
            }
        }
        if (t < 64) z0n[t] = (half_t)xnext;   // x(ts+1)
        __syncthreads();
    }
#undef DOT4
}

// ---------------- head: in-place gelu(cfc@Wh1.T+bh1)@Wh2.T + bh2 ----------------
__global__ __launch_bounds__(256) void k_head(float* io,
                                              const float* __restrict__ Wh1,
                                              const float* __restrict__ bh1,
                                              const float* __restrict__ Wh2T,
                                              const float* __restrict__ bh2)
{
    const int bt = blockIdx.x * 256 + threadIdx.x;
    float c32[32];
    const float4* cp = (const float4*)(io + (size_t)bt * 32);
#pragma unroll
    for (int k = 0; k < 8; ++k) {
        float4 v = cp[k];
        c32[4 * k] = v.x; c32[4 * k + 1] = v.y; c32[4 * k + 2] = v.z; c32[4 * k + 3] = v.w;
    }
    float acc[32];
#pragma unroll
    for (int o = 0; o < 32; ++o) acc[o] = bh2[o];
#pragma unroll 1
    for (int h = 0; h < HPn; ++h) {
        float ss = bh1[h];
        const float* w1r = Wh1 + (size_t)h * 32;
#pragma unroll
        for (int k = 0; k < 32; ++k) ss += c32[k] * w1r[k];
        float g = 0.5f * ss * (1.f + erff(ss * 0.70710678118654752440f));
        const float* w2r = Wh2T + (size_t)h * 32;
#pragma unroll
        for (int o = 0; o < 32; ++o) acc[o] += g * w2r[o];
    }
    float4* op = (float4*)(io + (size_t)bt * 32);
#pragma unroll
    for (int k = 0; k < 8; ++k) {
        float4 v;
        v.x = acc[4 * k]; v.y = acc[4 * k + 1]; v.z = acc[4 * k + 2]; v.w = acc[4 * k + 3];
        op[k] = v;
    }
}

// ---------------- launch ----------------
extern "C" void kernel_launch(void* const* d_in, const int* in_sizes, int n_in,
                              void* d_out, int out_size, void* d_ws, size_t ws_size,
                              hipStream_t stream)
{
    (void)in_sizes; (void)n_in; (void)out_size; (void)ws_size;
    const float* x      = (const float*)d_in[0];
    const float* Wp     = (const float*)d_in[1];
    const float* bp     = (const float*)d_in[2];
    const float* Wff1_0 = (const float*)d_in[3];
    const float* bff1_0 = (const float*)d_in[4];
    const float* Wff2_0 = (const float*)d_in[5];
    const float* bff2_0 = (const float*)d_in[6];
    const float* Wta_0  = (const float*)d_in[7];
    const float* bta_0  = (const float*)d_in[8];
    const float* Wtb_0  = (const float*)d_in[9];
    const float* btb_0  = (const float*)d_in[10];
    const unsigned char* mask_0 = (const unsigned char*)d_in[11];
    const float* Wff1_1 = (const float*)d_in[12];
    const float* bff1_1 = (const float*)d_in[13];
    const float* Wff2_1 = (const float*)d_in[14];
    const float* bff2_1 = (const float*)d_in[15];
    const float* Wta_1  = (const float*)d_in[16];
    const float* bta_1  = (const float*)d_in[17];
    const float* Wtb_1  = (const float*)d_in[18];
    const float* btb_1  = (const float*)d_in[19];
    const unsigned char* mask_1 = (const unsigned char*)d_in[20];
    const float* Wff1_2 = (const float*)d_in[21];
    const float* bff1_2 = (const float*)d_in[22];
    const float* Wff2_2 = (const float*)d_in[23];
    const float* bff2_2 = (const float*)d_in[24];
    const float* Wta_2  = (const float*)d_in[25];
    const float* bta_2  = (const float*)d_in[26];
    const float* Wtb_2  = (const float*)d_in[27];
    const float* btb_2  = (const float*)d_in[28];
    const unsigned char* mask_2 = (const unsigned char*)d_in[29];
    const float* Wh1    = (const float*)d_in[30];
    const float* bh1    = (const float*)d_in[31];
    const float* Wh2    = (const float*)d_in[32];
    const float* bh2    = (const float*)d_in[33];

    float* ws = (float*)d_ws;
    size_t o = 0;
    float* Wh0s = ws + o; o += (size_t)R0c * U0c;
    float* Wx0s = ws + o; o += (size_t)R0c * HPn;
    float* b0s  = ws + o; o += R0c; o += 3;
    float* Wcb  = ws + o; o += (size_t)R0c * DINn;
    float* b0c  = ws + o; o += R0c; o += 3;
    float* W1s  = ws + o; o += (size_t)R1c * C1c;
    float* b1s  = ws + o; o += R1c; o += 1;
    float* W2s  = ws + o; o += (size_t)R2c * C2c;
    float* b2s  = ws + o; o += R2c;
    float* Wh2T = ws + o; o += (size_t)HPn * 32;
    half_t* W0h = (half_t*)(ws + o); o += (size_t)R0c * 224 / 2;
    half_t* W1h = (half_t*)(ws + o); o += (size_t)R1c * 224 / 2;
    half_t* W2h = (half_t*)(ws + o); o += (size_t)R2c * 128 / 2;

    k_stack<<<128, 256, 0, stream>>>(Wff1_0, bff1_0, Wff2_0, bff2_0, Wta_0, bta_0, Wtb_0, btb_0,
                                     mask_0, U0c, C0c, HPn, Wx0s, Wh0s, b0s);
    k_stack<<<64, 256, 0, stream>>>(Wff1_1, bff1_1, Wff2_1, bff2_1, Wta_1, bta_1, Wtb_1, btb_1,
                                    mask_1, U1c, C1c, C1c, W1s, W1s, b1s);
    k_stack<<<16, 256, 0, stream>>>(Wff1_2, bff1_2, Wff2_2, bff2_2, Wta_2, bta_2, Wtb_2, btb_2,
                                    mask_2, U2c, C2c, C2c, W2s, W2s, b2s);
    k_comb<<<R0c, DINn, 0, stream>>>(Wx0s, Wp, Wcb);
    k_biasc<<<32, 256, 0, stream>>>(Wx0s, bp, b0s, b0c, Wh2, Wh2T);
    k_pack<<<320, 256, 0, stream>>>(Wcb, Wh0s, W1s, W2s, W0h, W1h, W2h);
    k_scan<<<BBn, 512, 0, stream>>>(W0h, W1h, W2h, b0c, b1s, b2s, x, (float*)d_out);
    k_head<<<(int)(BTn / 256), 256, 0, stream>>>((float*)d_out, Wh1, bh1, Wh2T, bh2);
}

// Round 5
// 4700.727 us; speedup vs baseline: 1.0705x; 1.0276x over previous
//
#include <hip/hip_runtime.h>
#include <cstdint>
#include <cstddef>

typedef _Float16 half_t;
typedef half_t half2_t __attribute__((ext_vector_type(2)));

static constexpr int TTs = 2048;   // timesteps
static constexpr int BBn = 64;     // batch
static constexpr int DINn = 64;    // input dim
static constexpr int HPn  = 256;   // proj dim
static constexpr int U0c = 135, C0c = 391, R0c = 405;   // layer0
static constexpr int U1c = 89,  C1c = 224, R1c = 267;   // layer1
static constexpr int U2c = 32,  C2c = 121, R2c = 96;    // layer2
static constexpr size_t BTn = (size_t)BBn * TTs;        // 131072

// ---------------- math helpers ----------------
__device__ __forceinline__ float tanh_f(float x) {
    return 1.f - __fdividef(2.f, __expf(2.f * x) + 1.f);
}
__device__ __forceinline__ float sigm_f(float x) {
    return __fdividef(1.f, 1.f + __expf(-x));
}
__device__ __forceinline__ float cfc_comb(float y0, float y1, float y2) {
    float f1 = tanh_f(y0), f2 = tanh_f(y1), ti = sigm_f(y2);
    return f1 + ti * (f2 - f1);
}
// quad butterfly sum via DPP (VALU pipe, no LDS)
__device__ __forceinline__ float qsum(float v) {
    v += __builtin_bit_cast(float, __builtin_amdgcn_update_dpp(
             0, __builtin_bit_cast(int, v), 0xB1, 0xF, 0xF, true));  // [1,0,3,2]
    v += __builtin_bit_cast(float, __builtin_amdgcn_update_dpp(
             0, __builtin_bit_cast(int, v), 0x4E, 0xF, 0xF, true));  // [2,3,0,1]
    return v;
}
__device__ __forceinline__ half2_t h2(unsigned u) { return __builtin_bit_cast(half2_t, u); }

// ---------------- mask dtype probe ----------------
__device__ __forceinline__ int mask_mode(const unsigned char* mp) {
    const unsigned* wp = (const unsigned*)mp;
    bool all01 = true, allf = true;
    for (int k = 0; k < 64; ++k) {
        unsigned w = wp[k];
        all01 = all01 && (w == 0u || w == 1u);
        allf  = allf  && (w == 0u || w == 0x3F800000u);
    }
    if (all01) return 0;
    if (allf)  return 1;
    return 2;
}
__device__ __forceinline__ bool mget(const unsigned char* mp, int mode, int idx) {
    if (mode == 0) return ((const int*)mp)[idx] != 0;
    if (mode == 1) return ((const float*)mp)[idx] != 0.f;
    return mp[idx] != 0;
}

// ---------------- prep: stack + mask weights ----------------
__global__ void k_stack(const float* __restrict__ Wff1, const float* __restrict__ bff1,
                        const float* __restrict__ Wff2, const float* __restrict__ bff2,
                        const float* __restrict__ Wta,  const float* __restrict__ bta,
                        const float* __restrict__ Wtb,  const float* __restrict__ btb,
                        const unsigned char* __restrict__ maskraw,
                        int u, int c, int split,
                        float* __restrict__ outA, float* __restrict__ outB,
                        float* __restrict__ bias_out)
{
    const int mode = mask_mode(maskraw);
    const int total = 3 * u * c + 3 * u;
    for (int idx = blockIdx.x * blockDim.x + threadIdx.x; idx < total;
         idx += gridDim.x * blockDim.x) {
        if (idx < 3 * u * c) {
            int m = idx / (u * c);
            int rem = idx - m * u * c;
            int r = rem / c;
            int k = rem - r * c;
            float v;
            if (m == 2) {
                v = Wta[r * c + k] + Wtb[r * c + k];
            } else {
                bool mk = mget(maskraw, mode, r * c + k);
                float w = (m == 0) ? Wff1[r * c + k] : Wff2[r * c + k];
                v = mk ? w : 0.f;
            }
            int R = m * u + r;
            if (k < split) outA[(size_t)R * split + k] = v;
            else           outB[(size_t)R * (c - split) + (k - split)] = v;
        } else {
            int j = idx - 3 * u * c;
            int m = j / u, r = j - m * u;
            bias_out[j] = (m == 0) ? bff1[r] : ((m == 1) ? bff2[r] : (bta[r] + btb[r]));
        }
    }
}

// ---------------- prep: Wcomb = Wx0s (405x256) @ Wp (256x64) ----------------
__global__ void k_comb(const float* __restrict__ Wx0s, const float* __restrict__ Wp,
                       float* __restrict__ Wcomb)
{
    const int r = blockIdx.x;
    const int d = threadIdx.x;
    float acc = 0.f;
    for (int k = 0; k < HPn; ++k) acc += Wx0s[(size_t)r * HPn + k] * Wp[(size_t)k * DINn + d];
    Wcomb[(size_t)r * DINn + d] = acc;
}

// ---------------- prep: folded bias + Wh2 transpose ----------------
__global__ void k_biasc(const float* __restrict__ Wx0s, const float* __restrict__ bp,
                        const float* __restrict__ b0, float* __restrict__ b0c,
                        const float* __restrict__ Wh2, float* __restrict__ Wh2T)
{
    const int i = blockIdx.x * blockDim.x + threadIdx.x;
    if (i < R0c) {
        float a = b0[i];
        for (int k = 0; k < HPn; ++k) a += Wx0s[(size_t)i * HPn + k] * bp[k];
        b0c[i] = a;
    }
    if (i < HPn * 32) {
        int h = i >> 5, o = i & 31;
        Wh2T[i] = Wh2[(size_t)o * HPn + h];
    }
}

// ---------------- prep: pack weights to padded fp16 ----------------
// W0h (405,224): [Wcb:64 | Wh0s:135 | 0:25]; W1h (267,224); W2h (96,128): [W2s:121|0:7]
__global__ void k_pack(const float* __restrict__ Wcb, const float* __restrict__ Wh0s,
                       const float* __restrict__ W1s, const float* __restrict__ W2s,
                       half_t* __restrict__ W0h, half_t* __restrict__ W1h,
                       half_t* __restrict__ W2h)
{
    const int N0 = R0c * 224, N1 = R1c * 224, N2 = R2c * 128;
    for (int idx = blockIdx.x * blockDim.x + threadIdx.x; idx < N0 + N1 + N2;
         idx += gridDim.x * blockDim.x) {
        if (idx < N0) {
            int r = idx / 224, c = idx - r * 224;
            float v = (c < 64) ? Wcb[(size_t)r * 64 + c]
                               : ((c < 199) ? Wh0s[(size_t)r * 135 + (c - 64)] : 0.f);
            W0h[idx] = (half_t)v;
        } else if (idx < N0 + N1) {
            int i = idx - N0;
            W1h[i] = (half_t)W1s[i];
        } else {
            int i = idx - N0 - N1;
            int r = i / 128, c = i - r * 128;
            W2h[i] = (half_t)((c < 121) ? W2s[(size_t)r * 121 + c] : 0.f);
        }
    }
}

// ---------------- the recurrent scan: 64 blocks x 512 threads ----------------
// Quad-per-unit column-split (s = t>>2 slot 0..127, q = t&3 chunk).
// Every quad owns EXACTLY 2 units (128*2 = 256 = 135 L0 + 89 L1 + 32 L2):
//   primary  = layer0 unit uA = s                      (phase A)
//   secondary: s<=88 -> layer1 unit s (phase B); s in 96..99/112..114 ->
//              layer0 unit 128../132.. (phase A, waves 6/7); else layer2 unit
//              (phase C).
// Weights live in 42 named uint4 SSA values (no arrays -> no alloca/scratch);
// amdgpu_waves_per_eu(2,2) pins the VGPR budget at 256.
// 3 gate rows per unit are quad-local: DPP qsum + in-lane combine; 3 barriers.
__global__ __attribute__((amdgpu_flat_work_group_size(512, 512),
                          amdgpu_waves_per_eu(2, 2)))
void k_scan(
    const half_t* __restrict__ W0h,   // (405,224)
    const half_t* __restrict__ W1h,   // (267,224)
    const half_t* __restrict__ W2h,   // (96,128)
    const float* __restrict__ b0c,    // (405)
    const float* __restrict__ b1s,    // (267)
    const float* __restrict__ b2s,    // (96)
    const float* __restrict__ x,      // (B,T,64)
    float* __restrict__ cfc)          // (B,T,32)
{
    const int t = threadIdx.x;
    const int b = blockIdx.x;
    const int s = t >> 2;     // slot 0..127
    const int q = t & 3;      // column chunk

    __shared__ float4 z0v[2][28];   // 224 halfs: [x:64 | h0:135 | 0:25]
    __shared__ float4 z1v[2][28];   // 224 halfs: [h0:135 | h1:89]
    __shared__ float4 z2v[2][16];   // 128 halfs: [h1:89 | h2:32 | 0:7]

    {
        float4* zz = (float4*)z0v;
        for (int i = t; i < 56 + 56 + 32; i += 512) zz[i] = make_float4(0.f, 0.f, 0.f, 0.f);
    }

    // ---- roles ----
    const int uA = s;                               // primary layer0 unit
    const bool isB  = (s <= 88);
    const bool isA2 = (s >= 96 && s <= 99) || (s >= 112 && s <= 114);
    const bool isC  = !isB && !isA2;
    int uS;                                         // secondary unit index
    if (isB)       uS = s;
    else if (isA2) uS = (s <= 99) ? 128 + (s - 96) : 132 + (s - 112);
    else           uS = (s <= 95) ? (s - 89) : ((s <= 111) ? 7 + (s - 100) : 19 + (s - 115));

    // ---- primary weights: 21 named uint4 ----
    uint4 a00,a01,a02,a03,a04,a05,a06;
    uint4 a10,a11,a12,a13,a14,a15,a16;
    uint4 a20,a21,a22,a23,a24,a25,a26;
    {
        const uint4* p0 = (const uint4*)(W0h + (size_t)(uA      ) * 224 + 56 * q);
        const uint4* p1 = (const uint4*)(W0h + (size_t)(uA + 135) * 224 + 56 * q);
        const uint4* p2 = (const uint4*)(W0h + (size_t)(uA + 270) * 224 + 56 * q);
        a00=p0[0]; a01=p0[1]; a02=p0[2]; a03=p0[3]; a04=p0[4]; a05=p0[5]; a06=p0[6];
        a10=p1[0]; a11=p1[1]; a12=p1[2]; a13=p1[3]; a14=p1[4]; a15=p1[5]; a16=p1[6];
        a20=p2[0]; a21=p2[1]; a22=p2[2]; a23=p2[3]; a24=p2[4]; a25=p2[5]; a26=p2[6];
    }
    // ---- secondary weights: 21 named uint4 (C uses 4 per row) ----
    uint4 b00,b01,b02,b03,b04,b05,b06;
    uint4 b10,b11,b12,b13,b14,b15,b16;
    uint4 b20,b21,b22,b23,b24,b25,b26;
    {
        const half_t* base; int row0, rstr, pitch, coff;
        if (isB)       { base = W1h; row0 = uS; rstr = 89;  pitch = 224; coff = 56 * q; }
        else if (isA2) { base = W0h; row0 = uS; rstr = 135; pitch = 224; coff = 56 * q; }
        else           { base = W2h; row0 = uS; rstr = 32;  pitch = 128; coff = 32 * q; }
        const uint4* p0 = (const uint4*)(base + (size_t)row0 * pitch + coff);
        const uint4* p1 = (const uint4*)(base + (size_t)(row0 + rstr) * pitch + coff);
        const uint4* p2 = (const uint4*)(base + (size_t)(row0 + 2 * rstr) * pitch + coff);
        const uint4 z4 = make_uint4(0u, 0u, 0u, 0u);
        b00=p0[0]; b01=p0[1]; b02=p0[2]; b03=p0[3];
        b10=p1[0]; b11=p1[1]; b12=p1[2]; b13=p1[3];
        b20=p2[0]; b21=p2[1]; b22=p2[2]; b23=p2[3];
        if (!isC) {
            b04=p0[4]; b05=p0[5]; b06=p0[6];
            b14=p1[4]; b15=p1[5]; b16=p1[6];
            b24=p2[4]; b25=p2[5]; b26=p2[6];
        } else {
            b04=z4; b05=z4; b06=z4; b14=z4; b15=z4; b16=z4; b24=z4; b25=z4; b26=z4;
        }
    }

    // ---- biases ----
    const float bA0 = b0c[uA], bA1 = b0c[135 + uA], bA2 = b0c[270 + uA];
    float bS0, bS1, bS2;
    if (isB)       { bS0 = b1s[uS]; bS1 = b1s[89 + uS];  bS2 = b1s[178 + uS]; }
    else if (isA2) { bS0 = b0c[uS]; bS1 = b0c[135 + uS]; bS2 = b0c[270 + uS]; }
    else           { bS0 = b2s[uS]; bS1 = b2s[32 + uS];  bS2 = b2s[64 + uS]; }

    const float* xb = x + (size_t)b * TTs * DINn;
    float* cfb = cfc + (size_t)b * TTs * 32;

    __syncthreads();
    if (t < 64) ((half_t*)&z0v[0][0])[t] = (half_t)xb[t];   // x(0)
    __syncthreads();

#define DOTU(acc, W) \
    acc = __builtin_amdgcn_fdot2(h2((W).x), v0, acc, false); \
    acc = __builtin_amdgcn_fdot2(h2((W).y), v1, acc, false); \
    acc = __builtin_amdgcn_fdot2(h2((W).z), v2, acc, false); \
    acc = __builtin_amdgcn_fdot2(h2((W).w), v3, acc, false);

#define PHA(J, A0w, A1w, A2w, B0w, B1w, B2w) { \
    float4 f = zcA[J]; \
    half2_t v0 = __builtin_bit_cast(half2_t, f.x); \
    half2_t v1 = __builtin_bit_cast(half2_t, f.y); \
    half2_t v2 = __builtin_bit_cast(half2_t, f.z); \
    half2_t v3 = __builtin_bit_cast(half2_t, f.w); \
    DOTU(a0, A0w) DOTU(a1, A1w) DOTU(a2, A2w) \
    if (isA2) { DOTU(c0, B0w) DOTU(c1, B1w) DOTU(c2, B2w) } }

#define PHB(J, B0w, B1w, B2w) { \
    float4 f = zcB[J]; \
    half2_t v0 = __builtin_bit_cast(half2_t, f.x); \
    half2_t v1 = __builtin_bit_cast(half2_t, f.y); \
    half2_t v2 = __builtin_bit_cast(half2_t, f.z); \
    half2_t v3 = __builtin_bit_cast(half2_t, f.w); \
    DOTU(c0, B0w) DOTU(c1, B1w) DOTU(c2, B2w) }

#pragma unroll 1
    for (int ts = 0; ts < TTs; ++ts) {
        const int p = ts & 1;
        half_t* z0n = (half_t*)&z0v[p ^ 1][0];
        half_t* z1c = (half_t*)&z1v[p][0];
        half_t* z1n = (half_t*)&z1v[p ^ 1][0];
        half_t* z2c = (half_t*)&z2v[p][0];
        half_t* z2n = (half_t*)&z2v[p ^ 1][0];

        float xnext = 0.f;
        if (t < 64) {
            int tn = (ts + 1 < TTs) ? ts + 1 : ts;
            xnext = xb[(size_t)tn * DINn + t];
        }

        // ================= phase A : layer0 over z0=[x|h0] =================
        {
            const float4* zcA = &z0v[p][q * 7];
            float a0 = 0.f, a1 = 0.f, a2 = 0.f;
            float c0 = 0.f, c1 = 0.f, c2 = 0.f;
            PHA(0, a00, a10, a20, b00, b10, b20)
            PHA(1, a01, a11, a21, b01, b11, b21)
            PHA(2, a02, a12, a22, b02, b12, b22)
            PHA(3, a03, a13, a23, b03, b13, b23)
            PHA(4, a04, a14, a24, b04, b14, b24)
            PHA(5, a05, a15, a25, b05, b15, b25)
            PHA(6, a06, a16, a26, b06, b16, b26)
            a0 = qsum(a0); a1 = qsum(a1); a2 = qsum(a2);
            if (q == 0) {
                float hn = cfc_comb(a0 + bA0, a1 + bA1, a2 + bA2);
                half_t hh = (half_t)hn;
                z1c[uA]      = hh;
                z0n[64 + uA] = hh;
            }
            if (isA2) {
                c0 = qsum(c0); c1 = qsum(c1); c2 = qsum(c2);
                if (q == 0) {
                    float hn = cfc_comb(c0 + bS0, c1 + bS1, c2 + bS2);
                    half_t hh = (half_t)hn;
                    z1c[uS]      = hh;
                    z0n[64 + uS] = hh;
                }
            }
        }
        __syncthreads();

        // ================= phase B : layer1 over z1=[h0|h1] ================
        if (isB) {
            const float4* zcB = &z1v[p][q * 7];
            float c0 = 0.f, c1 = 0.f, c2 = 0.f;
            PHB(0, b00, b10, b20)
            PHB(1, b01, b11, b21)
            PHB(2, b02, b12, b22)
            PHB(3, b03, b13, b23)
            PHB(4, b04, b14, b24)
            PHB(5, b05, b15, b25)
            PHB(6, b06, b16, b26)
            c0 = qsum(c0); c1 = qsum(c1); c2 = qsum(c2);
            if (q == 0) {
                float hn = cfc_comb(c0 + bS0, c1 + bS1, c2 + bS2);
                half_t hh = (half_t)hn;
                z2c[uS]       = hh;
                z1n[135 + uS] = hh;
            }
        }
        __syncthreads();

        // ================= phase C : layer2 over z2=[h1|h2] ================
        if (isC) {
            const float4* zcB = &z2v[p][q * 4];
            float c0 = 0.f, c1 = 0.f, c2 = 0.f;
            PHB(0, b00, b10, b20)
            PHB(1, b01, b11, b21)
            PHB(2, b02, b12, b22)
            PHB(3, b03, b13, b23)
            c0 = qsum(c0); c1 = qsum(c1); c2 = qsum(c2);
            if (q == 0) {
                float hn = cfc_comb(c0 + bS0, c1 + bS1, c2 + bS2);
                z2n[89 + uS] = (half_t)hn;
                cfb[(size_t)ts * 32 + uS] = hn;
            }
        }
        if (t < 64) z0n[t] = (half_t)xnext;   // x(ts+1)
        __syncthreads();
    }
#undef PHA
#undef PHB
#undef DOTU
}

// ---------------- head: in-place gelu(cfc@Wh1.T+bh1)@Wh2.T + bh2 ----------------
__global__ __launch_bounds__(256) void k_head(float* io,
                                              const float* __restrict__ Wh1,
                                              const float* __restrict__ bh1,
                                              const float* __restrict__ Wh2T,
                                              const float* __restrict__ bh2)
{
    const int bt = blockIdx.x * 256 + threadIdx.x;
    float c32[32];
    const float4* cp = (const float4*)(io + (size_t)bt * 32);
#pragma unroll
    for (int k = 0; k < 8; ++k) {
        float4 v = cp[k];
        c32[4 * k] = v.x; c32[4 * k + 1] = v.y; c32[4 * k + 2] = v.z; c32[4 * k + 3] = v.w;
    }
    float acc[32];
#pragma unroll
    for (int o = 0; o < 32; ++o) acc[o] = bh2[o];
#pragma unroll 1
    for (int h = 0; h < HPn; ++h) {
        float ss = bh1[h];
        const float* w1r = Wh1 + (size_t)h * 32;
#pragma unroll
        for (int k = 0; k < 32; ++k) ss += c32[k] * w1r[k];
        float g = 0.5f * ss * (1.f + erff(ss * 0.70710678118654752440f));
        const float* w2r = Wh2T + (size_t)h * 32;
#pragma unroll
        for (int o = 0; o < 32; ++o) acc[o] += g * w2r[o];
    }
    float4* op = (float4*)(io + (size_t)bt * 32);
#pragma unroll
    for (int k = 0; k < 8; ++k) {
        float4 v;
        v.x = acc[4 * k]; v.y = acc[4 * k + 1]; v.z = acc[4 * k + 2]; v.w = acc[4 * k + 3];
        op[k] = v;
    }
}

// ---------------- launch ----------------
extern "C" void kernel_launch(void* const* d_in, const int* in_sizes, int n_in,
                              void* d_out, int out_size, void* d_ws, size_t ws_size,
                              hipStream_t stream)
{
    (void)in_sizes; (void)n_in; (void)out_size; (void)ws_size;
    const float* x      = (const float*)d_in[0];
    const float* Wp     = (const float*)d_in[1];
    const float* bp     = (const float*)d_in[2];
    const float* Wff1_0 = (const float*)d_in[3];
    const float* bff1_0 = (const float*)d_in[4];
    const float* Wff2_0 = (const float*)d_in[5];
    const float* bff2_0 = (const float*)d_in[6];
    const float* Wta_0  = (const float*)d_in[7];
    const float* bta_0  = (const float*)d_in[8];
    const float* Wtb_0  = (const float*)d_in[9];
    const float* btb_0  = (const float*)d_in[10];
    const unsigned char* mask_0 = (const unsigned char*)d_in[11];
    const float* Wff1_1 = (const float*)d_in[12];
    const float* bff1_1 = (const float*)d_in[13];
    const float* Wff2_1 = (const float*)d_in[14];
    const float* bff2_1 = (const float*)d_in[15];
    const float* Wta_1  = (const float*)d_in[16];
    const float* bta_1  = (const float*)d_in[17];
    const float* Wtb_1  = (const float*)d_in[18];
    const float* btb_1  = (const float*)d_in[19];
    const unsigned char* mask_1 = (const unsigned char*)d_in[20];
    const float* Wff1_2 = (const float*)d_in[21];
    const float* bff1_2 = (const float*)d_in[22];
    const float* Wff2_2 = (const float*)d_in[23];
    const float* bff2_2 = (const float*)d_in[24];
    const float* Wta_2  = (const float*)d_in[25];
    const float* bta_2  = (const float*)d_in[26];
    const float* Wtb_2  = (const float*)d_in[27];
    const float* btb_2  = (const float*)d_in[28];
    const unsigned char* mask_2 = (const unsigned char*)d_in[29];
    const float* Wh1    = (const float*)d_in[30];
    const float* bh1    = (const float*)d_in[31];
    const float* Wh2    = (const float*)d_in[32];
    const float* bh2    = (const float*)d_in[33];

    float* ws = (float*)d_ws;
    size_t o = 0;
    float* Wh0s = ws + o; o += (size_t)R0c * U0c;
    float* Wx0s = ws + o; o += (size_t)R0c * HPn;
    float* b0s  = ws + o; o += R0c; o += 3;
    float* Wcb  = ws + o; o += (size_t)R0c * DINn;
    float* b0c  = ws + o; o += R0c; o += 3;
    float* W1s  = ws + o; o += (size_t)R1c * C1c;
    float* b1s  = ws + o; o += R1c; o += 1;
    float* W2s  = ws + o; o += (size_t)R2c * C2c;
    float* b2s  = ws + o; o += R2c;
    float* Wh2T = ws + o; o += (size_t)HPn * 32;
    half_t* W0h = (half_t*)(ws + o); o += (size_t)R0c * 224 / 2;
    half_t* W1h = (half_t*)(ws + o); o += (size_t)R1c * 224 / 2;
    half_t* W2h = (half_t*)(ws + o); o += (size_t)R2c * 128 / 2;

    k_stack<<<128, 256, 0, stream>>>(Wff1_0, bff1_0, Wff2_0, bff2_0, Wta_0, bta_0, Wtb_0, btb_0,
                                     mask_0, U0c, C0c, HPn, Wx0s, Wh0s, b0s);
    k_stack<<<64, 256, 0, stream>>>(Wff1_1, bff1_1, Wff2_1, bff2_1, Wta_1, bta_1, Wtb_1, btb_1,
                                    mask_1, U1c, C1c, C1c, W1s, W1s, b1s);
    k_stack<<<16, 256, 0, stream>>>(Wff1_2, bff1_2, Wff2_2, bff2_2, Wta_2, bta_2, Wtb_2, btb_2,
                                    mask_2, U2c, C2c, C2c, W2s, W2s, b2s);
    k_comb<<<R0c, DINn, 0, stream>>>(Wx0s, Wp, Wcb);
    k_biasc<<<32, 256, 0, stream>>>(Wx0s, bp, b0s, b0c, Wh2, Wh2T);
    k_pack<<<320, 256, 0, stream>>>(Wcb, Wh0s, W1s, W2s, W0h, W1h, W2h);
    k_scan<<<BBn, 512, 0, stream>>>(W0h, W1h, W2h, b0c, b1s, b2s, x, (float*)d_out);
    k_head<<<(int)(BTn / 256), 256, 0, stream>>>((float*)d_out, Wh1, bh1, Wh2T, bh2);
}

// Round 6
// 4644.321 us; speedup vs baseline: 1.0835x; 1.0121x over previous
//
#include <hip/hip_runtime.h>
#include <cstdint>
#include <cstddef>

typedef _Float16 half_t;
typedef half_t half2_t __attribute__((ext_vector_type(2)));

static constexpr int TTs = 2048;   // timesteps
static constexpr int BBn = 64;     // batch
static constexpr int DINn = 64;    // input dim
static constexpr int HPn  = 256;   // proj dim
static constexpr int U0c = 135, C0c = 391, R0c = 405;   // layer0
static constexpr int U1c = 89,  C1c = 224, R1c = 267;   // layer1
static constexpr int U2c = 32,  C2c = 121, R2c = 96;    // layer2
static constexpr size_t BTn = (size_t)BBn * TTs;        // 131072

// ---------------- math helpers ----------------
__device__ __forceinline__ float tanh_f(float x) {
    return 1.f - __fdividef(2.f, __expf(2.f * x) + 1.f);
}
__device__ __forceinline__ float sigm_f(float x) {
    return __fdividef(1.f, 1.f + __expf(-x));
}
__device__ __forceinline__ float cfc_comb(float y0, float y1, float y2) {
    float f1 = tanh_f(y0), f2 = tanh_f(y1), ti = sigm_f(y2);
    return f1 + ti * (f2 - f1);
}
// quad butterfly sum via DPP (VALU pipe, no LDS)
__device__ __forceinline__ float qsum(float v) {
    v += __builtin_bit_cast(float, __builtin_amdgcn_update_dpp(
             0, __builtin_bit_cast(int, v), 0xB1, 0xF, 0xF, true));  // [1,0,3,2]
    v += __builtin_bit_cast(float, __builtin_amdgcn_update_dpp(
             0, __builtin_bit_cast(int, v), 0x4E, 0xF, 0xF, true));  // [2,3,0,1]
    return v;
}
__device__ __forceinline__ half2_t h2(unsigned u) { return __builtin_bit_cast(half2_t, u); }

// ---------------- mask dtype probe ----------------
__device__ __forceinline__ int mask_mode(const unsigned char* mp) {
    const unsigned* wp = (const unsigned*)mp;
    bool all01 = true, allf = true;
    for (int k = 0; k < 64; ++k) {
        unsigned w = wp[k];
        all01 = all01 && (w == 0u || w == 1u);
        allf  = allf  && (w == 0u || w == 0x3F800000u);
    }
    if (all01) return 0;
    if (allf)  return 1;
    return 2;
}
__device__ __forceinline__ bool mget(const unsigned char* mp, int mode, int idx) {
    if (mode == 0) return ((const int*)mp)[idx] != 0;
    if (mode == 1) return ((const float*)mp)[idx] != 0.f;
    return mp[idx] != 0;
}

// ---------------- prep: stack + mask weights ----------------
__global__ void k_stack(const float* __restrict__ Wff1, const float* __restrict__ bff1,
                        const float* __restrict__ Wff2, const float* __restrict__ bff2,
                        const float* __restrict__ Wta,  const float* __restrict__ bta,
                        const float* __restrict__ Wtb,  const float* __restrict__ btb,
                        const unsigned char* __restrict__ maskraw,
                        int u, int c, int split,
                        float* __restrict__ outA, float* __restrict__ outB,
                        float* __restrict__ bias_out)
{
    const int mode = mask_mode(maskraw);
    const int total = 3 * u * c + 3 * u;
    for (int idx = blockIdx.x * blockDim.x + threadIdx.x; idx < total;
         idx += gridDim.x * blockDim.x) {
        if (idx < 3 * u * c) {
            int m = idx / (u * c);
            int rem = idx - m * u * c;
            int r = rem / c;
            int k = rem - r * c;
            float v;
            if (m == 2) {
                v = Wta[r * c + k] + Wtb[r * c + k];
            } else {
                bool mk = mget(maskraw, mode, r * c + k);
                float w = (m == 0) ? Wff1[r * c + k] : Wff2[r * c + k];
                v = mk ? w : 0.f;
            }
            int R = m * u + r;
            if (k < split) outA[(size_t)R * split + k] = v;
            else           outB[(size_t)R * (c - split) + (k - split)] = v;
        } else {
            int j = idx - 3 * u * c;
            int m = j / u, r = j - m * u;
            bias_out[j] = (m == 0) ? bff1[r] : ((m == 1) ? bff2[r] : (bta[r] + btb[r]));
        }
    }
}

// ---------------- prep: Wcomb = Wx0s (405x256) @ Wp (256x64) ----------------
__global__ void k_comb(const float* __restrict__ Wx0s, const float* __restrict__ Wp,
                       float* __restrict__ Wcomb)
{
    const int r = blockIdx.x;
    const int d = threadIdx.x;
    float acc = 0.f;
    for (int k = 0; k < HPn; ++k) acc += Wx0s[(size_t)r * HPn + k] * Wp[(size_t)k * DINn + d];
    Wcomb[(size_t)r * DINn + d] = acc;
}

// ---------------- prep: folded bias + Wh2 transpose ----------------
__global__ void k_biasc(const float* __restrict__ Wx0s, const float* __restrict__ bp,
                        const float* __restrict__ b0, float* __restrict__ b0c,
                        const float* __restrict__ Wh2, float* __restrict__ Wh2T)
{
    const int i = blockIdx.x * blockDim.x + threadIdx.x;
    if (i < R0c) {
        float a = b0[i];
        for (int k = 0; k < HPn; ++k) a += Wx0s[(size_t)i * HPn + k] * bp[k];
        b0c[i] = a;
    }
    if (i < HPn * 32) {
        int h = i >> 5, o = i & 31;
        Wh2T[i] = Wh2[(size_t)o * HPn + h];
    }
}

// ---------------- prep: pack weights to padded fp16 ----------------
// W0h (405,224): [Wcb:64 | Wh0s:135 | 0:25]; W1h (267,224); W2h (96,128): [W2s:121|0:7]
__global__ void k_pack(const float* __restrict__ Wcb, const float* __restrict__ Wh0s,
                       const float* __restrict__ W1s, const float* __restrict__ W2s,
                       half_t* __restrict__ W0h, half_t* __restrict__ W1h,
                       half_t* __restrict__ W2h)
{
    const int N0 = R0c * 224, N1 = R1c * 224, N2 = R2c * 128;
    for (int idx = blockIdx.x * blockDim.x + threadIdx.x; idx < N0 + N1 + N2;
         idx += gridDim.x * blockDim.x) {
        if (idx < N0) {
            int r = idx / 224, c = idx - r * 224;
            float v = (c < 64) ? Wcb[(size_t)r * 64 + c]
                               : ((c < 199) ? Wh0s[(size_t)r * 135 + (c - 64)] : 0.f);
            W0h[idx] = (half_t)v;
        } else if (idx < N0 + N1) {
            int i = idx - N0;
            W1h[i] = (half_t)W1s[i];
        } else {
            int i = idx - N0 - N1;
            int r = i / 128, c = i - r * 128;
            W2h[i] = (half_t)((c < 121) ? W2s[(size_t)r * 121 + c] : 0.f);
        }
    }
}

// pin: make a loaded uint4's components opaque (produced-by-volatile-asm) so
// the register allocator cannot REMATERIALIZE the load inside the scan loop.
#define PIN4(v) asm volatile("" : "+v"((v).x), "+v"((v).y), "+v"((v).z), "+v"((v).w))

// ---------------- the recurrent scan: 64 blocks x 512 threads ----------------
// Quad-per-unit column-split (s = t>>2 slot 0..127, q = t&3 chunk).
// Every quad owns EXACTLY 2 units (128*2 = 256 = 135 L0 + 89 L1 + 32 L2):
//   primary  = layer0 unit uA = s                      (phase A)
//   secondary: s<=88 -> layer1 unit s (phase B); s in 96..99/112..114 ->
//              layer0 unit 128../132.. (phase A); else layer2 unit (phase C).
// Weights: 42 named uint4 SSA values, PINNED against rematerialization.
// amdgpu_waves_per_eu(2,2) -> 256-VGPR budget. 3 barriers/step.
__global__ __attribute__((amdgpu_flat_work_group_size(512, 512),
                          amdgpu_waves_per_eu(2, 2)))
void k_scan(
    const half_t* __restrict__ W0h,   // (405,224)
    const half_t* __restrict__ W1h,   // (267,224)
    const half_t* __restrict__ W2h,   // (96,128)
    const float* __restrict__ b0c,    // (405)
    const float* __restrict__ b1s,    // (267)
    const float* __restrict__ b2s,    // (96)
    const float* __restrict__ x,      // (B,T,64)
    float* __restrict__ cfc)          // (B,T,32)
{
    const int t = threadIdx.x;
    const int b = blockIdx.x;
    const int s = t >> 2;     // slot 0..127
    const int q = t & 3;      // column chunk

    __shared__ float4 z0v[2][28];   // 224 halfs: [x:64 | h0:135 | 0:25]
    __shared__ float4 z1v[2][28];   // 224 halfs: [h0:135 | h1:89]
    __shared__ float4 z2v[2][16];   // 128 halfs: [h1:89 | h2:32 | 0:7]

    {
        float4* zz = (float4*)z0v;
        for (int i = t; i < 56 + 56 + 32; i += 512) zz[i] = make_float4(0.f, 0.f, 0.f, 0.f);
    }

    // ---- roles ----
    const int uA = s;                               // primary layer0 unit
    const bool isB  = (s <= 88);
    const bool isA2 = (s >= 96 && s <= 99) || (s >= 112 && s <= 114);
    const bool isC  = !isB && !isA2;
    int uS;                                         // secondary unit index
    if (isB)       uS = s;
    else if (isA2) uS = (s <= 99) ? 128 + (s - 96) : 132 + (s - 112);
    else           uS = (s <= 95) ? (s - 89) : ((s <= 111) ? 7 + (s - 100) : 19 + (s - 115));

    // ---- primary weights: 21 named uint4 ----
    uint4 a00,a01,a02,a03,a04,a05,a06;
    uint4 a10,a11,a12,a13,a14,a15,a16;
    uint4 a20,a21,a22,a23,a24,a25,a26;
    {
        const uint4* p0 = (const uint4*)(W0h + (size_t)(uA      ) * 224 + 56 * q);
        const uint4* p1 = (const uint4*)(W0h + (size_t)(uA + 135) * 224 + 56 * q);
        const uint4* p2 = (const uint4*)(W0h + (size_t)(uA + 270) * 224 + 56 * q);
        a00=p0[0]; a01=p0[1]; a02=p0[2]; a03=p0[3]; a04=p0[4]; a05=p0[5]; a06=p0[6];
        a10=p1[0]; a11=p1[1]; a12=p1[2]; a13=p1[3]; a14=p1[4]; a15=p1[5]; a16=p1[6];
        a20=p2[0]; a21=p2[1]; a22=p2[2]; a23=p2[3]; a24=p2[4]; a25=p2[5]; a26=p2[6];
    }
    // ---- secondary weights: 21 named uint4 (C uses 4 per row) ----
    uint4 b00,b01,b02,b03,b04,b05,b06;
    uint4 b10,b11,b12,b13,b14,b15,b16;
    uint4 b20,b21,b22,b23,b24,b25,b26;
    {
        const half_t* base; int row0, rstr, pitch, coff;
        if (isB)       { base = W1h; row0 = uS; rstr = 89;  pitch = 224; coff = 56 * q; }
        else if (isA2) { base = W0h; row0 = uS; rstr = 135; pitch = 224; coff = 56 * q; }
        else           { base = W2h; row0 = uS; rstr = 32;  pitch = 128; coff = 32 * q; }
        const uint4* p0 = (const uint4*)(base + (size_t)row0 * pitch + coff);
        const uint4* p1 = (const uint4*)(base + (size_t)(row0 + rstr) * pitch + coff);
        const uint4* p2 = (const uint4*)(base + (size_t)(row0 + 2 * rstr) * pitch + coff);
        const uint4 z4 = make_uint4(0u, 0u, 0u, 0u);
        b00=p0[0]; b01=p0[1]; b02=p0[2]; b03=p0[3];
        b10=p1[0]; b11=p1[1]; b12=p1[2]; b13=p1[3];
        b20=p2[0]; b21=p2[1]; b22=p2[2]; b23=p2[3];
        if (!isC) {
            b04=p0[4]; b05=p0[5]; b06=p0[6];
            b14=p1[4]; b15=p1[5]; b16=p1[6];
            b24=p2[4]; b25=p2[5]; b26=p2[6];
        } else {
            b04=z4; b05=z4; b06=z4; b14=z4; b15=z4; b16=z4; b24=z4; b25=z4; b26=z4;
        }
    }

    // ---- FORCE residency: opaque-asm pins (remat now illegal) ----
    PIN4(a00); PIN4(a01); PIN4(a02); PIN4(a03); PIN4(a04); PIN4(a05); PIN4(a06);
    PIN4(a10); PIN4(a11); PIN4(a12); PIN4(a13); PIN4(a14); PIN4(a15); PIN4(a16);
    PIN4(a20); PIN4(a21); PIN4(a22); PIN4(a23); PIN4(a24); PIN4(a25); PIN4(a26);
    PIN4(b00); PIN4(b01); PIN4(b02); PIN4(b03); PIN4(b04); PIN4(b05); PIN4(b06);
    PIN4(b10); PIN4(b11); PIN4(b12); PIN4(b13); PIN4(b14); PIN4(b15); PIN4(b16);
    PIN4(b20); PIN4(b21); PIN4(b22); PIN4(b23); PIN4(b24); PIN4(b25); PIN4(b26);

    // ---- biases ----
    const float bA0 = b0c[uA], bA1 = b0c[135 + uA], bA2 = b0c[270 + uA];
    float bS0, bS1, bS2;
    if (isB)       { bS0 = b1s[uS]; bS1 = b1s[89 + uS];  bS2 = b1s[178 + uS]; }
    else if (isA2) { bS0 = b0c[uS]; bS1 = b0c[135 + uS]; bS2 = b0c[270 + uS]; }
    else           { bS0 = b2s[uS]; bS1 = b2s[32 + uS];  bS2 = b2s[64 + uS]; }

    const float* xb = x + (size_t)b * TTs * DINn;
    float* cfb = cfc + (size_t)b * TTs * 32;

    __syncthreads();
    if (t < 64) ((half_t*)&z0v[0][0])[t] = (half_t)xb[t];   // x(0)
    __syncthreads();

#define DOTU(acc, W) \
    acc = __builtin_amdgcn_fdot2(h2((W).x), v0, acc, false); \
    acc = __builtin_amdgcn_fdot2(h2((W).y), v1, acc, false); \
    acc = __builtin_amdgcn_fdot2(h2((W).z), v2, acc, false); \
    acc = __builtin_amdgcn_fdot2(h2((W).w), v3, acc, false);

#define PHA(J, A0w, A1w, A2w, B0w, B1w, B2w) { \
    float4 f = zcA[J]; \
    half2_t v0 = __builtin_bit_cast(half2_t, f.x); \
    half2_t v1 = __builtin_bit_cast(half2_t, f.y); \
    half2_t v2 = __builtin_bit_cast(half2_t, f.z); \
    half2_t v3 = __builtin_bit_cast(half2_t, f.w); \
    DOTU(a0, A0w) DOTU(a1, A1w) DOTU(a2, A2w) \
    if (isA2) { DOTU(c0, B0w) DOTU(c1, B1w) DOTU(c2, B2w) } }

#define PHB(J, B0w, B1w, B2w) { \
    float4 f = zcB[J]; \
    half2_t v0 = __builtin_bit_cast(half2_t, f.x); \
    half2_t v1 = __builtin_bit_cast(half2_t, f.y); \
    half2_t v2 = __builtin_bit_cast(half2_t, f.z); \
    half2_t v3 = __builtin_bit_cast(half2_t, f.w); \
    DOTU(c0, B0w) DOTU(c1, B1w) DOTU(c2, B2w) }

#pragma unroll 1
    for (int ts = 0; ts < TTs; ++ts) {
        const int p = ts & 1;
        half_t* z0n = (half_t*)&z0v[p ^ 1][0];
        half_t* z1c = (half_t*)&z1v[p][0];
        half_t* z1n = (half_t*)&z1v[p ^ 1][0];
        half_t* z2c = (half_t*)&z2v[p][0];
        half_t* z2n = (half_t*)&z2v[p ^ 1][0];

        float xnext = 0.f;
        if (t < 64) {
            int tn = (ts + 1 < TTs) ? ts + 1 : ts;
            xnext = xb[(size_t)tn * DINn + t];
        }

        // ================= phase A : layer0 over z0=[x|h0] =================
        {
            const float4* zcA = &z0v[p][q * 7];
            float a0 = 0.f, a1 = 0.f, a2 = 0.f;
            float c0 = 0.f, c1 = 0.f, c2 = 0.f;
            PHA(0, a00, a10, a20, b00, b10, b20)
            PHA(1, a01, a11, a21, b01, b11, b21)
            PHA(2, a02, a12, a22, b02, b12, b22)
            PHA(3, a03, a13, a23, b03, b13, b23)
            PHA(4, a04, a14, a24, b04, b14, b24)
            PHA(5, a05, a15, a25, b05, b15, b25)
            PHA(6, a06, a16, a26, b06, b16, b26)
            a0 = qsum(a0); a1 = qsum(a1); a2 = qsum(a2);
            if (q == 0) {
                float hn = cfc_comb(a0 + bA0, a1 + bA1, a2 + bA2);
                half_t hh = (half_t)hn;
                z1c[uA]      = hh;
                z0n[64 + uA] = hh;
            }
            if (isA2) {
                c0 = qsum(c0); c1 = qsum(c1); c2 = qsum(c2);
                if (q == 0) {
                    float hn = cfc_comb(c0 + bS0, c1 + bS1, c2 + bS2);
                    half_t hh = (half_t)hn;
                    z1c[uS]      = hh;
                    z0n[64 + uS] = hh;
                }
            }
        }
        __syncthreads();

        // ================= phase B : layer1 over z1=[h0|h1] ================
        if (isB) {
            const float4* zcB = &z1v[p][q * 7];
            float c0 = 0.f, c1 = 0.f, c2 = 0.f;
            PHB(0, b00, b10, b20)
            PHB(1, b01, b11, b21)
            PHB(2, b02, b12, b22)
            PHB(3, b03, b13, b23)
            PHB(4, b04, b14, b24)
            PHB(5, b05, b15, b25)
            PHB(6, b06, b16, b26)
            c0 = qsum(c0); c1 = qsum(c1); c2 = qsum(c2);
            if (q == 0) {
                float hn = cfc_comb(c0 + bS0, c1 + bS1, c2 + bS2);
                half_t hh = (half_t)hn;
                z2c[uS]       = hh;
                z1n[135 + uS] = hh;
            }
        }
        __syncthreads();

        // ================= phase C : layer2 over z2=[h1|h2] ================
        if (isC) {
            const float4* zcB = &z2v[p][q * 4];
            float c0 = 0.f, c1 = 0.f, c2 = 0.f;
            PHB(0, b00, b10, b20)
            PHB(1, b01, b11, b21)
            PHB(2, b02, b12, b22)
            PHB(3, b03, b13, b23)
            c0 = qsum(c0); c1 = qsum(c1); c2 = qsum(c2);
            if (q == 0) {
                float hn = cfc_comb(c0 + bS0, c1 + bS1, c2 + bS2);
                z2n[89 + uS] = (half_t)hn;
                cfb[(size_t)ts * 32 + uS] = hn;
            }
        }
        if (t < 64) z0n[t] = (half_t)xnext;   // x(ts+1)
        __syncthreads();
    }
#undef PHA
#undef PHB
#undef DOTU
}

// ---------------- head: in-place gelu(cfc@Wh1.T+bh1)@Wh2.T + bh2 ----------------
__global__ __launch_bounds__(256) void k_head(float* io,
                                              const float* __restrict__ Wh1,
                                              const float* __restrict__ bh1,
                                              const float* __restrict__ Wh2T,
                                              const float* __restrict__ bh2)
{
    const int bt = blockIdx.x * 256 + threadIdx.x;
    float c32[32];
    const float4* cp = (const float4*)(io + (size_t)bt * 32);
#pragma unroll
    for (int k = 0; k < 8; ++k) {
        float4 v = cp[k];
        c32[4 * k] = v.x; c32[4 * k + 1] = v.y; c32[4 * k + 2] = v.z; c32[4 * k + 3] = v.w;
    }
    float acc[32];
#pragma unroll
    for (int o = 0; o < 32; ++o) acc[o] = bh2[o];
#pragma unroll 1
    for (int h = 0; h < HPn; ++h) {
        float ss = bh1[h];
        const float* w1r = Wh1 + (size_t)h * 32;
#pragma unroll
        for (int k = 0; k < 32; ++k) ss += c32[k] * w1r[k];
        float g = 0.5f * ss * (1.f + erff(ss * 0.70710678118654752440f));
        const float* w2r = Wh2T + (size_t)h * 32;
#pragma unroll
        for (int o = 0; o < 32; ++o) acc[o] += g * w2r[o];
    }
    float4* op = (float4*)(io + (size_t)bt * 32);
#pragma unroll
    for (int k = 0; k < 8; ++k) {
        float4 v;
        v.x = acc[4 * k]; v.y = acc[4 * k + 1]; v.z = acc[4 * k + 2]; v.w = acc[4 * k + 3];
        op[k] = v;
    }
}

// ---------------- launch ----------------
extern "C" void kernel_launch(void* const* d_in, const int* in_sizes, int n_in,
                              void* d_out, int out_size, void* d_ws, size_t ws_size,
                              hipStream_t stream)
{
    (void)in_sizes; (void)n_in; (void)out_size; (void)ws_size;
    const float* x      = (const float*)d_in[0];
    const float* Wp     = (const float*)d_in[1];
    const float* bp     = (const float*)d_in[2];
    const float* Wff1_0 = (const float*)d_in[3];
    const float* bff1_0 = (const float*)d_in[4];
    const float* Wff2_0 = (const float*)d_in[5];
    const float* bff2_0 = (const float*)d_in[6];
    const float* Wta_0  = (const float*)d_in[7];
    const float* bta_0  = (const float*)d_in[8];
    const float* Wtb_0  = (const float*)d_in[9];
    const float* btb_0  = (const float*)d_in[10];
    const unsigned char* mask_0 = (const unsigned char*)d_in[11];
    const float* Wff1_1 = (const float*)d_in[12];
    const float* bff1_1 = (const float*)d_in[13];
    const float* Wff2_1 = (const float*)d_in[14];
    const float* bff2_1 = (const float*)d_in[15];
    const float* Wta_1  = (const float*)d_in[16];
    const float* bta_1  = (const float*)d_in[17];
    const float* Wtb_1  = (const float*)d_in[18];
    const float* btb_1  = (const float*)d_in[19];
    const unsigned char* mask_1 = (const unsigned char*)d_in[20];
    const float* Wff1_2 = (const float*)d_in[21];
    const float* bff1_2 = (const float*)d_in[22];
    const float* Wff2_2 = (const float*)d_in[23];
    const float* bff2_2 = (const float*)d_in[24];
    const float* Wta_2  = (const float*)d_in[25];
    const float* bta_2  = (const float*)d_in[26];
    const float* Wtb_2  = (const float*)d_in[27];
    const float* btb_2  = (const float*)d_in[28];
    const unsigned char* mask_2 = (const unsigned char*)d_in[29];
    const float* Wh1    = (const float*)d_in[30];
    const float* bh1    = (const float*)d_in[31];
    const float* Wh2    = (const float*)d_in[32];
    const float* bh2    = (const float*)d_in[33];

    float* ws = (float*)d_ws;
    size_t o = 0;
    float* Wh0s = ws + o; o += (size_t)R0c * U0c;
    float* Wx0s = ws + o; o += (size_t)R0c * HPn;
    float* b0s  = ws + o; o += R0c; o += 3;
    float* Wcb  = ws + o; o += (size_t)R0c * DINn;
    float* b0c  = ws + o; o += R0c; o += 3;
    float* W1s  = ws + o; o += (size_t)R1c * C1c;
    float* b1s  = ws + o; o += R1c; o += 1;
    float* W2s  = ws + o; o += (size_t)R2c * C2c;
    float* b2s  = ws + o; o += R2c;
    float* Wh2T = ws + o; o += (size_t)HPn * 32;
    half_t* W0h = (half_t*)(ws + o); o += (size_t)R0c * 224 / 2;
    half_t* W1h = (half_t*)(ws + o); o += (size_t)R1c * 224 / 2;
    half_t* W2h = (half_t*)(ws + o); o += (size_t)R2c * 128 / 2;

    k_stack<<<128, 256, 0, stream>>>(Wff1_0, bff1_0, Wff2_0, bff2_0, Wta_0, bta_0, Wtb_0, btb_0,
                                     mask_0, U0c, C0c, HPn, Wx0s, Wh0s, b0s);
    k_stack<<<64, 256, 0, stream>>>(Wff1_1, bff1_1, Wff2_1, bff2_1, Wta_1, bta_1, Wtb_1, btb_1,
                                    mask_1, U1c, C1c, C1c, W1s, W1s, b1s);
    k_stack<<<16, 256, 0, stream>>>(Wff1_2, bff1_2, Wff2_2, bff2_2, Wta_2, bta_2, Wtb_2, btb_2,
                                    mask_2, U2c, C2c, C2c, W2s, W2s, b2s);
    k_comb<<<R0c, DINn, 0, stream>>>(Wx0s, Wp, Wcb);
    k_biasc<<<32, 256, 0, stream>>>(Wx0s, bp, b0s, b0c, Wh2, Wh2T);
    k_pack<<<320, 256, 0, stream>>>(Wcb, Wh0s, W1s, W2s, W0h, W1h, W2h);
    k_scan<<<BBn, 512, 0, stream>>>(W0h, W1h, W2h, b0c, b1s, b2s, x, (float*)d_out);
    k_head<<<(int)(BTn / 256), 256, 0, stream>>>((float*)d_out, Wh1, bh1, Wh2T, bh2);
}